// Round 1
// baseline (1709.055 us; speedup 1.0000x reference)
//
#include <hip/hip_runtime.h>
#include <hip/hip_bf16.h>
#include <math.h>

#define NN 2048          // n_nodes
#define NH 8             // heads
#define LRALPHA 0.2f
#define MAXD 2048        // max possible degree (= NN)

static __device__ __forceinline__ float lrelu(float x){ return x > 0.f ? x : LRALPHA * x; }
static __device__ __forceinline__ float elu(float x){ return x > 0.f ? x : expm1f(x); }

// ---------------- CSR build (deterministic, sorted by column) ----------------
__global__ void k_count(const float* __restrict__ adj, int* __restrict__ deg) {
    int gw   = (blockIdx.x * blockDim.x + threadIdx.x) >> 6;   // wave id = row
    int lane = threadIdx.x & 63;
    if (gw >= NN) return;
    const float* row = adj + (size_t)gw * NN;
    int cnt = 0;
    for (int j = lane; j < NN; j += 64) cnt += (row[j] > 0.f) ? 1 : 0;
    #pragma unroll
    for (int off = 32; off; off >>= 1) cnt += __shfl_down(cnt, off);
    if (lane == 0) deg[gw] = cnt;
}

__global__ void k_scan(const int* __restrict__ deg, int* __restrict__ rp) {
    __shared__ int a[NN], b[NN];
    int t = threadIdx.x;                       // 1024 threads
    for (int i = t; i < NN; i += 1024) a[i] = deg[i];
    __syncthreads();
    int* src = a; int* dst = b;
    for (int off = 1; off < NN; off <<= 1) {
        for (int i = t; i < NN; i += 1024)
            dst[i] = src[i] + (i >= off ? src[i - off] : 0);
        __syncthreads();
        int* tmp = src; src = dst; dst = tmp;
    }
    for (int i = t; i < NN; i += 1024) rp[i + 1] = src[i];
    if (t == 0) rp[0] = 0;
}

__global__ void k_fill(const float* __restrict__ adj, const int* __restrict__ rp,
                       int* __restrict__ ci) {
    int gw   = (blockIdx.x * blockDim.x + threadIdx.x) >> 6;
    int lane = threadIdx.x & 63;
    if (gw >= NN) return;
    const float* row = adj + (size_t)gw * NN;
    int base = rp[gw];
    for (int j0 = 0; j0 < NN; j0 += 64) {
        bool v = row[j0 + lane] > 0.f;
        unsigned long long m = __ballot(v);
        int pos = __popcll(m & ((1ULL << lane) - 1ULL));
        if (v) ci[base + pos] = j0 + lane;
        base += __popcll(m);
    }
}

// ---------------- fp32 tiled GEMM: C[M,Ncol] = A[M,K] @ B ----------------
// MODE 0: B is plain row-major [K, Ncol].
// MODE 1: B is Wh [NH, K, hid]; logical col c -> head = c>>hs, d = c & (hid-1).
//         (64-wide col tiles never straddle a head since hid >= 128.)
template<int MODE>
__global__ __launch_bounds__(256) void k_gemm(
    const float* __restrict__ A, const float* __restrict__ B, float* __restrict__ C,
    int M, int Ncol, int K, int hs)
{
    __shared__ float As[16][68];   // [k][m], padded: float4-aligned rows, 2-way max conflict
    __shared__ float Bs[16][64];   // [k][c]
    int tid = threadIdx.x;
    int tx = tid & 15, ty = tid >> 4;
    int m0 = blockIdx.y * 64, c0 = blockIdx.x * 64;

    const float* Bt; int ldbt;
    if (MODE == 1) {
        int hid  = 1 << hs;
        int head = c0 >> hs;
        int d0   = c0 & (hid - 1);
        Bt   = B + (size_t)head * K * hid + d0;   // (k,c) -> Bt[k*hid + c]
        ldbt = hid;
    } else {
        Bt   = B + c0;
        ldbt = Ncol;
    }

    float acc[4][4] = {};
    int aRow = tid >> 2, aK4 = (tid & 3) * 4;
    int bK   = tid >> 4, bC4 = (tid & 15) * 4;

    for (int k0 = 0; k0 < K; k0 += 16) {
        float4 av = *(const float4*)(A  + (size_t)(m0 + aRow) * K    + k0 + aK4);
        float4 bv = *(const float4*)(Bt + (size_t)(k0 + bK)   * ldbt + bC4);
        As[aK4 + 0][aRow] = av.x; As[aK4 + 1][aRow] = av.y;
        As[aK4 + 2][aRow] = av.z; As[aK4 + 3][aRow] = av.w;
        *(float4*)&Bs[bK][bC4] = bv;
        __syncthreads();
        #pragma unroll
        for (int kk = 0; kk < 16; kk++) {
            float4 a = *(const float4*)&As[kk][ty * 4];
            float4 b = *(const float4*)&Bs[kk][tx * 4];
            acc[0][0] += a.x * b.x; acc[0][1] += a.x * b.y; acc[0][2] += a.x * b.z; acc[0][3] += a.x * b.w;
            acc[1][0] += a.y * b.x; acc[1][1] += a.y * b.y; acc[1][2] += a.y * b.z; acc[1][3] += a.y * b.w;
            acc[2][0] += a.z * b.x; acc[2][1] += a.z * b.y; acc[2][2] += a.z * b.z; acc[2][3] += a.z * b.w;
            acc[3][0] += a.w * b.x; acc[3][1] += a.w * b.y; acc[3][2] += a.w * b.z; acc[3][3] += a.w * b.w;
        }
        __syncthreads();
    }
    #pragma unroll
    for (int i = 0; i < 4; i++) {
        float4 v = make_float4(acc[i][0], acc[i][1], acc[i][2], acc[i][3]);
        *(float4*)(C + (size_t)(m0 + ty * 4 + i) * Ncol + c0 + tx * 4) = v;
    }
}

// ---------------- s1/s2 (or t1/t2): one wave per (head, node) ----------------
__global__ void k_s(const float* __restrict__ h, const float* __restrict__ a,
                    float* __restrict__ s1, float* __restrict__ s2,
                    int Hn, int hid, int HD)
{
    int gw   = (blockIdx.x * blockDim.x + threadIdx.x) >> 6;
    int lane = threadIdx.x & 63;
    if (gw >= Hn * NN) return;
    int head = gw >> 11;           // / NN
    int i    = gw & (NN - 1);
    const float* hr = h + (size_t)i * HD + head * hid;
    const float* a1 = a + (size_t)head * 2 * hid;
    const float* a2 = a1 + hid;
    float acc1 = 0.f, acc2 = 0.f;
    for (int d = lane; d < hid; d += 64) {
        float v = hr[d];
        acc1 += v * a1[d];
        acc2 += v * a2[d];
    }
    #pragma unroll
    for (int off = 32; off; off >>= 1) {
        acc1 += __shfl_down(acc1, off);
        acc2 += __shfl_down(acc2, off);
    }
    if (lane == 0) { s1[gw] = acc1; s2[gw] = acc2; }
}

// ------------- sparse masked softmax + aggregation, block per (node, head) -------------
__global__ __launch_bounds__(256) void k_agg(
    const float* __restrict__ hsrc, const float* __restrict__ s1, const float* __restrict__ s2,
    const int* __restrict__ rp, const int* __restrict__ ci,
    float* __restrict__ out, int hid, int HD, int HDout)
{
    __shared__ float w[MAXD];
    __shared__ int   cols[MAXD];
    __shared__ float red[8];
    int i = blockIdx.x, head = blockIdx.y;
    int tid = threadIdx.x, lane = tid & 63, wid = tid >> 6;
    int base = rp[i], deg = rp[i + 1] - base;
    float s1i = s1[head * NN + i];

    // phase A: scores + max
    float m = -1e30f;
    for (int k = tid; k < deg; k += 256) {
        int j = ci[base + k];
        float e = lrelu(s1i + s2[head * NN + j]);
        cols[k] = j; w[k] = e;
        m = fmaxf(m, e);
    }
    #pragma unroll
    for (int off = 32; off; off >>= 1) m = fmaxf(m, __shfl_down(m, off));
    if (lane == 0) red[wid] = m;
    __syncthreads();
    if (tid == 0) { float mm = red[0]; for (int q = 1; q < 4; q++) mm = fmaxf(mm, red[q]); red[4] = mm; }
    __syncthreads();
    m = red[4];

    // phase B: exp + sum
    float sum = 0.f;
    for (int k = tid; k < deg; k += 256) {
        float wv = expf(w[k] - m);
        w[k] = wv;
        sum += wv;
    }
    #pragma unroll
    for (int off = 32; off; off >>= 1) sum += __shfl_down(sum, off);
    if (lane == 0) red[wid] = sum;
    __syncthreads();
    if (tid == 0) red[5] = red[0] + red[1] + red[2] + red[3];
    __syncthreads();
    float inv = 1.f / red[5];

    // phase C: weighted gather of neighbor rows, elu, write
    const float* hcol = hsrc + head * hid;
    float* orow = out + (size_t)i * HDout + head * hid;
    for (int d = tid; d < hid; d += 256) {
        float acc = 0.f;
        #pragma unroll 4
        for (int k = 0; k < deg; k++)
            acc += w[k] * hcol[(size_t)cols[k] * HD + d];
        orow[d] = elu(acc * inv);
    }
}

// ---------------- host driver ----------------
extern "C" void kernel_launch(void* const* d_in, const int* in_sizes, int n_in,
                              void* d_out, int out_size, void* d_ws, size_t ws_size,
                              hipStream_t stream)
{
    const float* x   = (const float*)d_in[0];
    const float* adj = (const float*)d_in[1];
    struct L { int fin, hid, fout; };
    const L dims[6] = {{256,128,128},{128,256,256},{256,512,384},
                       {384,512,256},{256,256,128},{128,128,256}};

    char* ws = (char*)d_ws;
    size_t off = 0;
    auto alloc = [&](size_t bytes) -> void* {
        void* p = ws + off;
        off = (off + bytes + 255) & ~(size_t)255;
        return p;
    };
    int*   rp   = (int*)alloc((NN + 1) * sizeof(int));
    int*   deg  = (int*)alloc(NN * sizeof(int));
    int*   ci   = (int*)alloc((size_t)(1 << 20) * sizeof(int));   // nnz cap ~12x expected
    float* hbuf = (float*)alloc((size_t)NN * 4096 * sizeof(float));
    float* gbuf = (float*)alloc((size_t)NN * 4096 * sizeof(float));
    float* hob  = (float*)alloc((size_t)NN * 512 * sizeof(float));
    float* xb0  = (float*)alloc((size_t)NN * 512 * sizeof(float));
    float* xb1  = (float*)alloc((size_t)NN * 512 * sizeof(float));
    float* s1   = (float*)alloc((size_t)NH * NN * sizeof(float));
    float* s2   = (float*)alloc((size_t)NH * NN * sizeof(float));
    float* t1   = (float*)alloc(NN * sizeof(float));
    float* t2   = (float*)alloc(NN * sizeof(float));

    k_count<<<NN / 4, 256, 0, stream>>>(adj, deg);
    k_scan <<<1, 1024, 0, stream>>>(deg, rp);
    k_fill <<<NN / 4, 256, 0, stream>>>(adj, rp, ci);

    const float* cur = x;
    for (int l = 0; l < 6; l++) {
        int fin = dims[l].fin, hid = dims[l].hid, fout = dims[l].fout;
        int HD = NH * hid;
        int hs = (hid == 128) ? 7 : (hid == 256) ? 8 : 9;
        const float* Wh = (const float*)d_in[2 + l * 4 + 0];
        const float* ah = (const float*)d_in[2 + l * 4 + 1];
        const float* Wo = (const float*)d_in[2 + l * 4 + 2];
        const float* ao = (const float*)d_in[2 + l * 4 + 3];

        // h = x @ Wh  (per-head, written as hcat [N, H*hid])
        dim3 g1(HD / 64, NN / 64);
        k_gemm<1><<<g1, 256, 0, stream>>>(cur, Wh, hbuf, NN, HD, fin, hs);
        // s1, s2
        k_s<<<(NH * NN) / 4, 256, 0, stream>>>(hbuf, ah, s1, s2, NH, hid, HD);
        // per-head masked softmax aggregation -> gbuf [N, H*hid] (elu'd)
        dim3 ga(NN, NH);
        k_agg<<<ga, 256, 0, stream>>>(hbuf, s1, s2, rp, ci, gbuf, hid, HD, HD);
        // ho = hcat @ Wo
        dim3 g2(fout / 64, NN / 64);
        k_gemm<0><<<g2, 256, 0, stream>>>(gbuf, Wo, hob, NN, fout, HD, 0);
        // t1, t2
        k_s<<<NN / 4, 256, 0, stream>>>(hob, ao, t1, t2, 1, fout, fout);
        // output attention head -> next layer input (or d_out)
        float* nxt = (l == 5) ? (float*)d_out : ((l & 1) ? xb1 : xb0);
        dim3 gb(NN, 1);
        k_agg<<<gb, 256, 0, stream>>>(hob, t1, t2, rp, ci, nxt, fout, fout, fout);
        cur = nxt;
    }
}

// Round 2
// 902.986 us; speedup vs baseline: 1.8927x; 1.8927x over previous
//
#include <hip/hip_runtime.h>
#include <hip/hip_bf16.h>
#include <math.h>

#define NN 2048          // n_nodes
#define NH 8             // heads
#define LRALPHA 0.2f
#define MAXD 2048

typedef short bf16x8 __attribute__((ext_vector_type(8)));
typedef float f32x4  __attribute__((ext_vector_type(4)));

static __device__ __forceinline__ float lrelu(float x){ return x > 0.f ? x : LRALPHA * x; }
static __device__ __forceinline__ float elu(float x){ return x > 0.f ? x : expm1f(x); }

// bf16 round-to-nearest-even via bit ops (finite inputs)
static __device__ __forceinline__ unsigned short f2bf(float v){
    unsigned u = __float_as_uint(v);
    unsigned r = (u + 0x7fffu + ((u >> 16) & 1u)) >> 16;
    return (unsigned short)r;
}
static __device__ __forceinline__ float bf2f(unsigned short b){
    return __uint_as_float(((unsigned)b) << 16);
}

static __device__ __forceinline__ void gload16(const void* g, void* l){
    __builtin_amdgcn_global_load_lds((const __attribute__((address_space(1))) void*)g,
                                     (__attribute__((address_space(3))) void*)l, 16, 0, 0);
}

// ---------------- CSR build (deterministic, sorted by column) ----------------
__global__ void k_count(const float* __restrict__ adj, int* __restrict__ deg) {
    int gw   = (blockIdx.x * blockDim.x + threadIdx.x) >> 6;
    int lane = threadIdx.x & 63;
    if (gw >= NN) return;
    const float* row = adj + (size_t)gw * NN;
    int cnt = 0;
    for (int j = lane; j < NN; j += 64) cnt += (row[j] > 0.f) ? 1 : 0;
    #pragma unroll
    for (int off = 32; off; off >>= 1) cnt += __shfl_down(cnt, off);
    if (lane == 0) deg[gw] = cnt;
}

__global__ void k_scan(const int* __restrict__ deg, int* __restrict__ rp) {
    __shared__ int a[NN], b[NN];
    int t = threadIdx.x;                       // 1024 threads
    for (int i = t; i < NN; i += 1024) a[i] = deg[i];
    __syncthreads();
    int* src = a; int* dst = b;
    for (int off = 1; off < NN; off <<= 1) {
        for (int i = t; i < NN; i += 1024)
            dst[i] = src[i] + (i >= off ? src[i - off] : 0);
        __syncthreads();
        int* tmp = src; src = dst; dst = tmp;
    }
    for (int i = t; i < NN; i += 1024) rp[i + 1] = src[i];
    if (t == 0) rp[0] = 0;
}

__global__ void k_fill(const float* __restrict__ adj, const int* __restrict__ rp,
                       int* __restrict__ ci) {
    int gw   = (blockIdx.x * blockDim.x + threadIdx.x) >> 6;
    int lane = threadIdx.x & 63;
    if (gw >= NN) return;
    const float* row = adj + (size_t)gw * NN;
    int base = rp[gw];
    for (int j0 = 0; j0 < NN; j0 += 64) {
        bool v = row[j0 + lane] > 0.f;
        unsigned long long m = __ballot(v);
        int pos = __popcll(m & ((1ULL << lane) - 1ULL));
        if (v) ci[base + pos] = j0 + lane;
        base += __popcll(m);
    }
}

// ---------------- split fp32 -> bf16 hi/lo (elementwise, for input x) ----------------
__global__ void k_split(const float* __restrict__ src, unsigned short* __restrict__ hi,
                        unsigned short* __restrict__ lo, int n4) {
    int i = blockIdx.x * 256 + threadIdx.x;
    if (i >= n4) return;
    float4 v = ((const float4*)src)[i];
    ushort4 h, l;
    h.x = f2bf(v.x); l.x = f2bf(v.x - bf2f(h.x));
    h.y = f2bf(v.y); l.y = f2bf(v.y - bf2f(h.y));
    h.z = f2bf(v.z); l.z = f2bf(v.z - bf2f(h.z));
    h.w = f2bf(v.w); l.w = f2bf(v.w - bf2f(h.w));
    ((ushort4*)hi)[i] = h;
    ((ushort4*)lo)[i] = l;
}

// ------- weight transpose + split: B[k][c] (fp32) -> Bt_hi/lo [c][k] (bf16) -------
// hs < 0: B is plain [K][Nc]. hs >= 0: B is Wh [NH][K][hid], c -> (head=c>>hs, d=c&(hid-1)).
__global__ __launch_bounds__(256) void k_tsplit(const float* __restrict__ B,
        unsigned short* __restrict__ bth, unsigned short* __restrict__ btl,
        int K, int Nc, int hs) {
    __shared__ float t[64][65];
    int tid = threadIdx.x;
    int kb = blockIdx.x * 64, cb = blockIdx.y * 64;
    #pragma unroll
    for (int i = 0; i < 16; i++) {
        int idx = i * 256 + tid;
        int kk = idx >> 6, cc = idx & 63;
        int c = cb + cc, k = kb + kk;
        float v;
        if (hs < 0) v = B[(size_t)k * Nc + c];
        else {
            int hid = 1 << hs; int head = c >> hs; int d = c & (hid - 1);
            v = B[((size_t)head * K + k) * hid + d];
        }
        t[kk][cc] = v;
    }
    __syncthreads();
    #pragma unroll
    for (int i = 0; i < 16; i++) {
        int idx = i * 256 + tid;
        int cc = idx >> 6, kk = idx & 63;
        float v = t[kk][cc];
        unsigned short h = f2bf(v);
        size_t o = (size_t)(cb + cc) * K + kb + kk;
        bth[o] = h;
        btl[o] = f2bf(v - bf2f(h));
    }
}

// ---------------- split-bf16 MFMA GEMM: C[M=2048][Nc] (+)= A[M][K] @ Bt[Nc][K]^T --------
// A as hi/lo bf16 [M][K] row-major; Bt as hi/lo bf16 [Nc][K] (i.e. B transposed).
// 128x128 tile, 4 waves, K-step 32, swizzled LDS staged via global_load_lds(16B).
__global__ __launch_bounds__(256) void k_mfma(
    const unsigned short* __restrict__ Ah, const unsigned short* __restrict__ Al,
    const unsigned short* __restrict__ Bh, const unsigned short* __restrict__ Bl,
    float* __restrict__ C, int Nc, int K, int Kc, int atom)
{
    __shared__ unsigned short lds[16384];   // 32KB: [0]=Ah [4096]=Al [8192]=Bh [12288]=Bl
    int tid = threadIdx.x, lane = tid & 63, w = tid >> 6;
    int m0 = blockIdx.y * 128, n0 = blockIdx.x * 128;
    int kbeg = blockIdx.z * Kc;

    // staging: slot s in [0,512), 16B each; LDS holds (row=s>>2, g=((s&3)-(row>>1))&3)
    int sA = tid, sB = 256 + tid;
    int ra = sA >> 2, ga = ((sA & 3) - (ra >> 1)) & 3;
    int rb = sB >> 2, gb = ((sB & 3) - (rb >> 1)) & 3;
    const unsigned short* pAh0 = Ah + (size_t)(m0 + ra) * K + kbeg + ga * 8;
    const unsigned short* pAh1 = Ah + (size_t)(m0 + rb) * K + kbeg + gb * 8;
    const unsigned short* pAl0 = Al + (size_t)(m0 + ra) * K + kbeg + ga * 8;
    const unsigned short* pAl1 = Al + (size_t)(m0 + rb) * K + kbeg + gb * 8;
    const unsigned short* pBh0 = Bh + (size_t)(n0 + ra) * K + kbeg + ga * 8;
    const unsigned short* pBh1 = Bh + (size_t)(n0 + rb) * K + kbeg + gb * 8;
    const unsigned short* pBl0 = Bl + (size_t)(n0 + ra) * K + kbeg + ga * 8;
    const unsigned short* pBl1 = Bl + (size_t)(n0 + rb) * K + kbeg + gb * 8;
    unsigned short* d0 = &lds[(w * 64) * 8];          // + lane*16B done by HW
    unsigned short* d1 = &lds[(256 + w * 64) * 8];

    // fragment LDS offsets (ushort units), swizzled to match staging
    int wr = w >> 1, wc = w & 1;
    int offA[4], offB[4];
    #pragma unroll
    for (int m = 0; m < 4; m++) {
        int row = wr * 64 + m * 16 + (lane & 15); int g = lane >> 4;
        offA[m] = (row * 4 + ((g + (row >> 1)) & 3)) * 8;
    }
    #pragma unroll
    for (int n = 0; n < 4; n++) {
        int row = wc * 64 + n * 16 + (lane & 15); int g = lane >> 4;
        offB[n] = (row * 4 + ((g + (row >> 1)) & 3)) * 8;
    }

    f32x4 acc[4][4];
    #pragma unroll
    for (int m = 0; m < 4; m++)
        #pragma unroll
        for (int n = 0; n < 4; n++) acc[m][n] = (f32x4){0.f, 0.f, 0.f, 0.f};

    int nk = Kc >> 5;
    for (int ks = 0; ks < nk; ks++) {
        gload16(pAh0, d0);          gload16(pAh1, d1);
        gload16(pAl0, d0 + 4096);   gload16(pAl1, d1 + 4096);
        gload16(pBh0, d0 + 8192);   gload16(pBh1, d1 + 8192);
        gload16(pBl0, d0 + 12288);  gload16(pBl1, d1 + 12288);
        pAh0 += 32; pAh1 += 32; pAl0 += 32; pAl1 += 32;
        pBh0 += 32; pBh1 += 32; pBl0 += 32; pBl1 += 32;
        __syncthreads();            // drains vmcnt(0): tiles ready
        bf16x8 ah[4], al[4], bh[4], bl[4];
        #pragma unroll
        for (int m = 0; m < 4; m++) {
            ah[m] = *(const bf16x8*)&lds[offA[m]];
            al[m] = *(const bf16x8*)&lds[4096 + offA[m]];
        }
        #pragma unroll
        for (int n = 0; n < 4; n++) {
            bh[n] = *(const bf16x8*)&lds[8192 + offB[n]];
            bl[n] = *(const bf16x8*)&lds[12288 + offB[n]];
        }
        #pragma unroll
        for (int m = 0; m < 4; m++)
            #pragma unroll
            for (int n = 0; n < 4; n++) {
                acc[m][n] = __builtin_amdgcn_mfma_f32_16x16x32_bf16(ah[m], bh[n], acc[m][n], 0, 0, 0);
                acc[m][n] = __builtin_amdgcn_mfma_f32_16x16x32_bf16(al[m], bh[n], acc[m][n], 0, 0, 0);
                acc[m][n] = __builtin_amdgcn_mfma_f32_16x16x32_bf16(ah[m], bl[n], acc[m][n], 0, 0, 0);
            }
        __syncthreads();            // protect LDS before next overwrite
    }

    // epilogue: C/D layout col=lane&15, row=(lane>>4)*4+reg
    #pragma unroll
    for (int m = 0; m < 4; m++)
        #pragma unroll
        for (int n = 0; n < 4; n++) {
            int row = m0 + wr * 64 + m * 16 + (lane >> 4) * 4;
            int col = n0 + wc * 64 + n * 16 + (lane & 15);
            #pragma unroll
            for (int r = 0; r < 4; r++) {
                float v = acc[m][n][r];
                float* p = &C[(size_t)(row + r) * Nc + col];
                if (atom) atomicAdd(p, v); else *p = v;
            }
        }
}

// ---------------- s1/s2 (or t1/t2): one wave per (head, node) ----------------
__global__ void k_s(const float* __restrict__ h, const float* __restrict__ a,
                    float* __restrict__ s1, float* __restrict__ s2,
                    int Hn, int hid, int HD)
{
    int gw   = (blockIdx.x * blockDim.x + threadIdx.x) >> 6;
    int lane = threadIdx.x & 63;
    if (gw >= Hn * NN) return;
    int head = gw >> 11;
    int i    = gw & (NN - 1);
    const float* hr = h + (size_t)i * HD + head * hid;
    const float* a1 = a + (size_t)head * 2 * hid;
    const float* a2 = a1 + hid;
    float acc1 = 0.f, acc2 = 0.f;
    for (int d = lane; d < hid; d += 64) {
        float v = hr[d];
        acc1 += v * a1[d];
        acc2 += v * a2[d];
    }
    #pragma unroll
    for (int off = 32; off; off >>= 1) {
        acc1 += __shfl_down(acc1, off);
        acc2 += __shfl_down(acc2, off);
    }
    if (lane == 0) { s1[gw] = acc1; s2[gw] = acc2; }
}

// ------------- sparse masked softmax + aggregation, block per (node, head) -------------
// Writes fp32 (optional) + bf16 hi/lo split of the elu output.
__global__ __launch_bounds__(256) void k_agg(
    const float* __restrict__ hsrc, const float* __restrict__ s1, const float* __restrict__ s2,
    const int* __restrict__ rp, const int* __restrict__ ci,
    float* __restrict__ outF, unsigned short* __restrict__ outH, unsigned short* __restrict__ outL,
    int hid, int HD, int HDout)
{
    __shared__ float w[MAXD];
    __shared__ int   cols[MAXD];
    __shared__ float red[8];
    int i = blockIdx.x, head = blockIdx.y;
    int tid = threadIdx.x, lane = tid & 63, wid = tid >> 6;
    int base = rp[i], deg = rp[i + 1] - base;
    float s1i = s1[head * NN + i];

    float m = -1e30f;
    for (int k = tid; k < deg; k += 256) {
        int j = ci[base + k];
        float e = lrelu(s1i + s2[head * NN + j]);
        cols[k] = j; w[k] = e;
        m = fmaxf(m, e);
    }
    #pragma unroll
    for (int off = 32; off; off >>= 1) m = fmaxf(m, __shfl_down(m, off));
    if (lane == 0) red[wid] = m;
    __syncthreads();
    if (tid == 0) { float mm = red[0]; for (int q = 1; q < 4; q++) mm = fmaxf(mm, red[q]); red[4] = mm; }
    __syncthreads();
    m = red[4];

    float sum = 0.f;
    for (int k = tid; k < deg; k += 256) {
        float wv = expf(w[k] - m);
        w[k] = wv;
        sum += wv;
    }
    #pragma unroll
    for (int off = 32; off; off >>= 1) sum += __shfl_down(sum, off);
    if (lane == 0) red[wid] = sum;
    __syncthreads();
    if (tid == 0) red[5] = red[0] + red[1] + red[2] + red[3];
    __syncthreads();
    float inv = 1.f / red[5];

    const float* hcol = hsrc + head * hid;
    size_t obase = (size_t)i * HDout + head * hid;
    for (int d = tid; d < hid; d += 256) {
        float acc = 0.f;
        #pragma unroll 4
        for (int k = 0; k < deg; k++)
            acc += w[k] * hcol[(size_t)cols[k] * HD + d];
        float val = elu(acc * inv);
        if (outF) outF[obase + d] = val;
        unsigned short h = f2bf(val);
        outH[obase + d] = h;
        outL[obase + d] = f2bf(val - bf2f(h));
    }
}

// ---------------- host driver ----------------
extern "C" void kernel_launch(void* const* d_in, const int* in_sizes, int n_in,
                              void* d_out, int out_size, void* d_ws, size_t ws_size,
                              hipStream_t stream)
{
    const float* x   = (const float*)d_in[0];
    const float* adj = (const float*)d_in[1];
    struct L { int fin, hid, fout; };
    const L dims[6] = {{256,128,128},{128,256,256},{256,512,384},
                       {384,512,256},{256,256,128},{128,128,256}};
    const int SKwh[6] = {2, 1, 1, 1, 1, 2};
    const int SKwo[6] = {16, 8, 8, 8, 16, 8};

    char* ws = (char*)d_ws;
    size_t off = 0;
    auto alloc = [&](size_t bytes) -> void* {
        void* p = ws + off;
        off = (off + bytes + 255) & ~(size_t)255;
        return p;
    };
    int*   rp   = (int*)alloc((NN + 1) * sizeof(int));
    int*   deg  = (int*)alloc(NN * sizeof(int));
    int*   ci   = (int*)alloc((size_t)(1 << 20) * sizeof(int));
    float* hbuf = (float*)alloc((size_t)NN * 4096 * sizeof(float));       // 32MB
    unsigned short* ghi = (unsigned short*)alloc((size_t)NN * 4096 * 2);  // 16MB
    unsigned short* glo = (unsigned short*)alloc((size_t)NN * 4096 * 2);  // 16MB
    float* hob = (float*)alloc((size_t)NN * 512 * sizeof(float));         // 4MB
    unsigned short* xhi = (unsigned short*)alloc((size_t)NN * 512 * 2);   // 2MB
    unsigned short* xlo = (unsigned short*)alloc((size_t)NN * 512 * 2);   // 2MB
    unsigned short* bth = (unsigned short*)alloc((size_t)4096 * 512 * 2); // 4MB
    unsigned short* btl = (unsigned short*)alloc((size_t)4096 * 512 * 2); // 4MB
    float* s1 = (float*)alloc((size_t)NH * NN * sizeof(float));
    float* s2 = (float*)alloc((size_t)NH * NN * sizeof(float));
    float* t1 = (float*)alloc(NN * sizeof(float));
    float* t2 = (float*)alloc(NN * sizeof(float));

    k_count<<<NN / 4, 256, 0, stream>>>(adj, deg);
    k_scan <<<1, 1024, 0, stream>>>(deg, rp);
    k_fill <<<NN / 4, 256, 0, stream>>>(adj, rp, ci);

    // split input x -> xhi/xlo
    k_split<<<(NN * 256 / 4 + 255) / 256, 256, 0, stream>>>(x, xhi, xlo, NN * 256 / 4);

    for (int l = 0; l < 6; l++) {
        int fin = dims[l].fin, hid = dims[l].hid, fout = dims[l].fout;
        int HD = NH * hid;
        int hs = (hid == 128) ? 7 : (hid == 256) ? 8 : 9;
        const float* Wh = (const float*)d_in[2 + l * 4 + 0];
        const float* ah = (const float*)d_in[2 + l * 4 + 1];
        const float* Wo = (const float*)d_in[2 + l * 4 + 2];
        const float* ao = (const float*)d_in[2 + l * 4 + 3];

        // --- h = x @ Wh ---
        dim3 gt1(fin / 64, HD / 64);
        k_tsplit<<<gt1, 256, 0, stream>>>(Wh, bth, btl, fin, HD, hs);
        int skh = SKwh[l];
        if (skh > 1) hipMemsetAsync(hbuf, 0, (size_t)NN * HD * 4, stream);
        dim3 gg1(HD / 128, NN / 128, skh);
        k_mfma<<<gg1, 256, 0, stream>>>(xhi, xlo, bth, btl, hbuf, HD, fin, fin / skh, skh > 1);

        k_s<<<(NH * NN) / 4, 256, 0, stream>>>(hbuf, ah, s1, s2, NH, hid, HD);
        dim3 ga(NN, NH);
        k_agg<<<ga, 256, 0, stream>>>(hbuf, s1, s2, rp, ci, nullptr, ghi, glo, hid, HD, HD);

        // --- ho = hcat @ Wo ---
        dim3 gt2(HD / 64, fout / 64);
        k_tsplit<<<gt2, 256, 0, stream>>>(Wo, bth, btl, HD, fout, -1);
        int sko = SKwo[l];
        hipMemsetAsync(hob, 0, (size_t)NN * fout * 4, stream);
        dim3 gg2(fout / 128, NN / 128, sko);
        k_mfma<<<gg2, 256, 0, stream>>>(ghi, glo, bth, btl, hob, fout, HD, HD / sko, 1);

        k_s<<<NN / 4, 256, 0, stream>>>(hob, ao, t1, t2, 1, fout, fout);
        float* outF = (l == 5) ? (float*)d_out : nullptr;
        k_agg<<<dim3(NN, 1), 256, 0, stream>>>(hob, t1, t2, rp, ci, outF, xhi, xlo, fout, fout, fout);
    }
}

// Round 3
// 847.524 us; speedup vs baseline: 2.0165x; 1.0654x over previous
//
#include <hip/hip_runtime.h>
#include <hip/hip_bf16.h>
#include <math.h>

#define NN 2048          // n_nodes
#define NH 8             // heads
#define LRALPHA 0.2f
#define CHUNK 256        // neighbors per online-softmax chunk

typedef short bf16x8 __attribute__((ext_vector_type(8)));
typedef float f32x4  __attribute__((ext_vector_type(4)));

static __device__ __forceinline__ float lrelu(float x){ return x > 0.f ? x : LRALPHA * x; }
static __device__ __forceinline__ float elu(float x){ return x > 0.f ? x : expm1f(x); }

// bf16 round-to-nearest-even via bit ops (finite inputs)
static __device__ __forceinline__ unsigned short f2bf(float v){
    unsigned u = __float_as_uint(v);
    unsigned r = (u + 0x7fffu + ((u >> 16) & 1u)) >> 16;
    return (unsigned short)r;
}
static __device__ __forceinline__ float bf2f(unsigned short b){
    return __uint_as_float(((unsigned)b) << 16);
}

static __device__ __forceinline__ void gload16(const void* g, void* l){
    __builtin_amdgcn_global_load_lds((const __attribute__((address_space(1))) void*)g,
                                     (__attribute__((address_space(3))) void*)l, 16, 0, 0);
}

// ---------------- CSR build (deterministic, sorted by column) ----------------
__global__ void k_count(const float* __restrict__ adj, int* __restrict__ deg) {
    int gw   = (blockIdx.x * blockDim.x + threadIdx.x) >> 6;
    int lane = threadIdx.x & 63;
    if (gw >= NN) return;
    const float* row = adj + (size_t)gw * NN;
    int cnt = 0;
    for (int j = lane; j < NN; j += 64) cnt += (row[j] > 0.f) ? 1 : 0;
    #pragma unroll
    for (int off = 32; off; off >>= 1) cnt += __shfl_down(cnt, off);
    if (lane == 0) deg[gw] = cnt;
}

__global__ void k_scan(const int* __restrict__ deg, int* __restrict__ rp) {
    __shared__ int a[NN], b[NN];
    int t = threadIdx.x;                       // 1024 threads
    for (int i = t; i < NN; i += 1024) a[i] = deg[i];
    __syncthreads();
    int* src = a; int* dst = b;
    for (int off = 1; off < NN; off <<= 1) {
        for (int i = t; i < NN; i += 1024)
            dst[i] = src[i] + (i >= off ? src[i - off] : 0);
        __syncthreads();
        int* tmp = src; src = dst; dst = tmp;
    }
    for (int i = t; i < NN; i += 1024) rp[i + 1] = src[i];
    if (t == 0) rp[0] = 0;
}

__global__ void k_fill(const float* __restrict__ adj, const int* __restrict__ rp,
                       int* __restrict__ ci) {
    int gw   = (blockIdx.x * blockDim.x + threadIdx.x) >> 6;
    int lane = threadIdx.x & 63;
    if (gw >= NN) return;
    const float* row = adj + (size_t)gw * NN;
    int base = rp[gw];
    for (int j0 = 0; j0 < NN; j0 += 64) {
        bool v = row[j0 + lane] > 0.f;
        unsigned long long m = __ballot(v);
        int pos = __popcll(m & ((1ULL << lane) - 1ULL));
        if (v) ci[base + pos] = j0 + lane;
        base += __popcll(m);
    }
}

// ---------------- split fp32 -> bf16 hi/lo (elementwise, for input x) ----------------
__global__ void k_split(const float* __restrict__ src, unsigned short* __restrict__ hi,
                        unsigned short* __restrict__ lo, int n4) {
    int i = blockIdx.x * 256 + threadIdx.x;
    if (i >= n4) return;
    float4 v = ((const float4*)src)[i];
    ushort4 h, l;
    h.x = f2bf(v.x); l.x = f2bf(v.x - bf2f(h.x));
    h.y = f2bf(v.y); l.y = f2bf(v.y - bf2f(h.y));
    h.z = f2bf(v.z); l.z = f2bf(v.z - bf2f(h.z));
    h.w = f2bf(v.w); l.w = f2bf(v.w - bf2f(h.w));
    ((ushort4*)hi)[i] = h;
    ((ushort4*)lo)[i] = l;
}

// ------- weight transpose + split: B[k][c] (fp32) -> Bt_hi/lo [c][k] (bf16) -------
__global__ __launch_bounds__(256) void k_tsplit(const float* __restrict__ B,
        unsigned short* __restrict__ bth, unsigned short* __restrict__ btl,
        int K, int Nc, int hs) {
    __shared__ float t[64][65];
    int tid = threadIdx.x;
    int kb = blockIdx.x * 64, cb = blockIdx.y * 64;
    #pragma unroll
    for (int i = 0; i < 16; i++) {
        int idx = i * 256 + tid;
        int kk = idx >> 6, cc = idx & 63;
        int c = cb + cc, k = kb + kk;
        float v;
        if (hs < 0) v = B[(size_t)k * Nc + c];
        else {
            int hid = 1 << hs; int head = c >> hs; int d = c & (hid - 1);
            v = B[((size_t)head * K + k) * hid + d];
        }
        t[kk][cc] = v;
    }
    __syncthreads();
    #pragma unroll
    for (int i = 0; i < 16; i++) {
        int idx = i * 256 + tid;
        int cc = idx >> 6, kk = idx & 63;
        float v = t[kk][cc];
        unsigned short h = f2bf(v);
        size_t o = (size_t)(cb + cc) * K + kb + kk;
        bth[o] = h;
        btl[o] = f2bf(v - bf2f(h));
    }
}

// ---------------- split-bf16 MFMA GEMM (unchanged from round 2) ----------------
__global__ __launch_bounds__(256) void k_mfma(
    const unsigned short* __restrict__ Ah, const unsigned short* __restrict__ Al,
    const unsigned short* __restrict__ Bh, const unsigned short* __restrict__ Bl,
    float* __restrict__ C, int Nc, int K, int Kc, int atom)
{
    __shared__ unsigned short lds[16384];
    int tid = threadIdx.x, lane = tid & 63, w = tid >> 6;
    int m0 = blockIdx.y * 128, n0 = blockIdx.x * 128;
    int kbeg = blockIdx.z * Kc;

    int sA = tid, sB = 256 + tid;
    int ra = sA >> 2, ga = ((sA & 3) - (ra >> 1)) & 3;
    int rb = sB >> 2, gb = ((sB & 3) - (rb >> 1)) & 3;
    const unsigned short* pAh0 = Ah + (size_t)(m0 + ra) * K + kbeg + ga * 8;
    const unsigned short* pAh1 = Ah + (size_t)(m0 + rb) * K + kbeg + gb * 8;
    const unsigned short* pAl0 = Al + (size_t)(m0 + ra) * K + kbeg + ga * 8;
    const unsigned short* pAl1 = Al + (size_t)(m0 + rb) * K + kbeg + gb * 8;
    const unsigned short* pBh0 = Bh + (size_t)(n0 + ra) * K + kbeg + ga * 8;
    const unsigned short* pBh1 = Bh + (size_t)(n0 + rb) * K + kbeg + gb * 8;
    const unsigned short* pBl0 = Bl + (size_t)(n0 + ra) * K + kbeg + ga * 8;
    const unsigned short* pBl1 = Bl + (size_t)(n0 + rb) * K + kbeg + gb * 8;
    unsigned short* d0 = &lds[(w * 64) * 8];
    unsigned short* d1 = &lds[(256 + w * 64) * 8];

    int wr = w >> 1, wc = w & 1;
    int offA[4], offB[4];
    #pragma unroll
    for (int m = 0; m < 4; m++) {
        int row = wr * 64 + m * 16 + (lane & 15); int g = lane >> 4;
        offA[m] = (row * 4 + ((g + (row >> 1)) & 3)) * 8;
    }
    #pragma unroll
    for (int n = 0; n < 4; n++) {
        int row = wc * 64 + n * 16 + (lane & 15); int g = lane >> 4;
        offB[n] = (row * 4 + ((g + (row >> 1)) & 3)) * 8;
    }

    f32x4 acc[4][4];
    #pragma unroll
    for (int m = 0; m < 4; m++)
        #pragma unroll
        for (int n = 0; n < 4; n++) acc[m][n] = (f32x4){0.f, 0.f, 0.f, 0.f};

    int nk = Kc >> 5;
    for (int ks = 0; ks < nk; ks++) {
        gload16(pAh0, d0);          gload16(pAh1, d1);
        gload16(pAl0, d0 + 4096);   gload16(pAl1, d1 + 4096);
        gload16(pBh0, d0 + 8192);   gload16(pBh1, d1 + 8192);
        gload16(pBl0, d0 + 12288);  gload16(pBl1, d1 + 12288);
        pAh0 += 32; pAh1 += 32; pAl0 += 32; pAl1 += 32;
        pBh0 += 32; pBh1 += 32; pBl0 += 32; pBl1 += 32;
        __syncthreads();
        bf16x8 ah[4], al[4], bh[4], bl[4];
        #pragma unroll
        for (int m = 0; m < 4; m++) {
            ah[m] = *(const bf16x8*)&lds[offA[m]];
            al[m] = *(const bf16x8*)&lds[4096 + offA[m]];
        }
        #pragma unroll
        for (int n = 0; n < 4; n++) {
            bh[n] = *(const bf16x8*)&lds[8192 + offB[n]];
            bl[n] = *(const bf16x8*)&lds[12288 + offB[n]];
        }
        #pragma unroll
        for (int m = 0; m < 4; m++)
            #pragma unroll
            for (int n = 0; n < 4; n++) {
                acc[m][n] = __builtin_amdgcn_mfma_f32_16x16x32_bf16(ah[m], bh[n], acc[m][n], 0, 0, 0);
                acc[m][n] = __builtin_amdgcn_mfma_f32_16x16x32_bf16(al[m], bh[n], acc[m][n], 0, 0, 0);
                acc[m][n] = __builtin_amdgcn_mfma_f32_16x16x32_bf16(ah[m], bl[n], acc[m][n], 0, 0, 0);
            }
        __syncthreads();
    }

    #pragma unroll
    for (int m = 0; m < 4; m++)
        #pragma unroll
        for (int n = 0; n < 4; n++) {
            int row = m0 + wr * 64 + m * 16 + (lane >> 4) * 4;
            int col = n0 + wc * 64 + n * 16 + (lane & 15);
            #pragma unroll
            for (int r = 0; r < 4; r++) {
                float v = acc[m][n][r];
                float* p = &C[(size_t)(row + r) * Nc + col];
                if (atom) atomicAdd(p, v); else *p = v;
            }
        }
}

// ---------------- s1/s2 (or t1/t2): one wave per (head, node) ----------------
__global__ void k_s(const float* __restrict__ h, const float* __restrict__ a,
                    float* __restrict__ s1, float* __restrict__ s2,
                    int Hn, int hid, int HD)
{
    int gw   = (blockIdx.x * blockDim.x + threadIdx.x) >> 6;
    int lane = threadIdx.x & 63;
    if (gw >= Hn * NN) return;
    int head = gw >> 11;
    int i    = gw & (NN - 1);
    const float* hr = h + (size_t)i * HD + head * hid;
    const float* a1 = a + (size_t)head * 2 * hid;
    const float* a2 = a1 + hid;
    float acc1 = 0.f, acc2 = 0.f;
    for (int d = lane; d < hid; d += 64) {
        float v = hr[d];
        acc1 += v * a1[d];
        acc2 += v * a2[d];
    }
    #pragma unroll
    for (int off = 32; off; off >>= 1) {
        acc1 += __shfl_down(acc1, off);
        acc2 += __shfl_down(acc2, off);
    }
    if (lane == 0) { s1[gw] = acc1; s2[gw] = acc2; }
}

// ------------- sparse masked softmax + aggregation, block per (node, head) -------------
// float4 gathers; neighbor loop split over G = 256/(hid/4) thread-groups with LDS
// tree-reduce; chunked online softmax (exact). Writes fp32 (opt) + bf16 hi/lo.
__global__ __launch_bounds__(256) void k_agg(
    const float* __restrict__ hsrc, const float* __restrict__ s1, const float* __restrict__ s2,
    const int* __restrict__ rp, const int* __restrict__ ci,
    float* __restrict__ outF, unsigned short* __restrict__ outH, unsigned short* __restrict__ outL,
    int hid, int HD, int HDout)
{
    __shared__ float  w[CHUNK];
    __shared__ int    cols[CHUNK];
    __shared__ float4 redbuf[256];
    __shared__ float  red[8];

    int i = blockIdx.x, head = blockIdx.y;
    int tid = threadIdx.x, lane = tid & 63, wid = tid >> 6;
    int base = rp[i], deg = rp[i + 1] - base;
    float s1i = s1[head * NN + i];
    const float* s2h = s2 + head * NN;

    int C4  = hid >> 2;           // float4 columns per head slice
    int G   = 256 / C4;           // neighbor groups (>=2 for hid<=512; 384->G=2)
    int col = tid % C4;
    int grp = tid / C4;
    bool active = grp < G;

    const float4* h4 = (const float4*)hsrc;
    int hoff4 = (head * hid) >> 2;
    int ld4   = HD >> 2;

    float m_run = -1e30f, s_run = 0.f;
    float4 acc = make_float4(0.f, 0.f, 0.f, 0.f);

    for (int k0 = 0; k0 < deg; k0 += CHUNK) {
        int n = min(CHUNK, deg - k0);
        __syncthreads();                         // protect w/cols reuse
        // scores + local max
        float m = -1e30f;
        for (int k = tid; k < n; k += 256) {
            int j = ci[base + k0 + k];
            float e = lrelu(s1i + s2h[j]);
            cols[k] = j; w[k] = e;
            m = fmaxf(m, e);
        }
        #pragma unroll
        for (int off = 32; off; off >>= 1) m = fmaxf(m, __shfl_down(m, off));
        if (lane == 0) red[wid] = m;
        __syncthreads();
        if (tid == 0) { float mm = red[0]; for (int q = 1; q < 4; q++) mm = fmaxf(mm, red[q]); red[4] = mm; }
        __syncthreads();
        float m2 = fmaxf(m_run, red[4]);

        // exp + local sum
        float sum = 0.f;
        for (int k = tid; k < n; k += 256) {
            float wv = expf(w[k] - m2);
            w[k] = wv;
            sum += wv;
        }
        #pragma unroll
        for (int off = 32; off; off >>= 1) sum += __shfl_down(sum, off);
        if (lane == 0) red[wid] = sum;
        __syncthreads();
        if (tid == 0) red[5] = red[0] + red[1] + red[2] + red[3];
        __syncthreads();
        float csum = red[5];

        float scale = expf(m_run - m2);          // exp(-inf)=0 first time
        s_run = s_run * scale + csum;
        acc.x *= scale; acc.y *= scale; acc.z *= scale; acc.w *= scale;
        m_run = m2;

        // gather: group grp takes neighbors k = grp, grp+G, ...
        if (active) {
            for (int k = grp; k < n; k += G) {
                float wv = w[k];
                float4 hv = h4[(size_t)cols[k] * ld4 + hoff4 + col];
                acc.x += wv * hv.x; acc.y += wv * hv.y;
                acc.z += wv * hv.z; acc.w += wv * hv.w;
            }
        }
    }

    // reduce acc across groups
    redbuf[tid] = acc;
    __syncthreads();
    if (grp == 0) {
        for (int g = 1; g < G; g++) {
            float4 o = redbuf[g * C4 + col];
            acc.x += o.x; acc.y += o.y; acc.z += o.z; acc.w += o.w;
        }
        float inv = 1.f / s_run;
        float4 val;
        val.x = elu(acc.x * inv); val.y = elu(acc.y * inv);
        val.z = elu(acc.z * inv); val.w = elu(acc.w * inv);
        size_t o4 = ((size_t)i * HDout + head * hid) / 4 + col;
        if (outF) ((float4*)outF)[o4] = val;
        ushort4 h, l;
        h.x = f2bf(val.x); l.x = f2bf(val.x - bf2f(h.x));
        h.y = f2bf(val.y); l.y = f2bf(val.y - bf2f(h.y));
        h.z = f2bf(val.z); l.z = f2bf(val.z - bf2f(h.z));
        h.w = f2bf(val.w); l.w = f2bf(val.w - bf2f(h.w));
        ((ushort4*)outH)[o4] = h;
        ((ushort4*)outL)[o4] = l;
    }
}

// ---------------- host driver ----------------
extern "C" void kernel_launch(void* const* d_in, const int* in_sizes, int n_in,
                              void* d_out, int out_size, void* d_ws, size_t ws_size,
                              hipStream_t stream)
{
    const float* x   = (const float*)d_in[0];
    const float* adj = (const float*)d_in[1];
    struct L { int fin, hid, fout; };
    const L dims[6] = {{256,128,128},{128,256,256},{256,512,384},
                       {384,512,256},{256,256,128},{128,128,256}};
    const int SKwh[6] = {2, 1, 1, 1, 1, 2};
    const int SKwo[6] = {16, 8, 8, 8, 16, 8};

    char* ws = (char*)d_ws;
    size_t off = 0;
    auto alloc = [&](size_t bytes) -> void* {
        void* p = ws + off;
        off = (off + bytes + 255) & ~(size_t)255;
        return p;
    };
    int*   rp   = (int*)alloc((NN + 1) * sizeof(int));
    int*   deg  = (int*)alloc(NN * sizeof(int));
    int*   ci   = (int*)alloc((size_t)(1 << 20) * sizeof(int));
    float* hbuf = (float*)alloc((size_t)NN * 4096 * sizeof(float));
    unsigned short* ghi = (unsigned short*)alloc((size_t)NN * 4096 * 2);
    unsigned short* glo = (unsigned short*)alloc((size_t)NN * 4096 * 2);
    float* hob = (float*)alloc((size_t)NN * 512 * sizeof(float));
    unsigned short* xhi = (unsigned short*)alloc((size_t)NN * 512 * 2);
    unsigned short* xlo = (unsigned short*)alloc((size_t)NN * 512 * 2);
    unsigned short* bth = (unsigned short*)alloc((size_t)4096 * 512 * 2);
    unsigned short* btl = (unsigned short*)alloc((size_t)4096 * 512 * 2);
    float* s1 = (float*)alloc((size_t)NH * NN * sizeof(float));
    float* s2 = (float*)alloc((size_t)NH * NN * sizeof(float));
    float* t1 = (float*)alloc(NN * sizeof(float));
    float* t2 = (float*)alloc(NN * sizeof(float));

    k_count<<<NN / 4, 256, 0, stream>>>(adj, deg);
    k_scan <<<1, 1024, 0, stream>>>(deg, rp);
    k_fill <<<NN / 4, 256, 0, stream>>>(adj, rp, ci);

    k_split<<<(NN * 256 / 4 + 255) / 256, 256, 0, stream>>>(x, xhi, xlo, NN * 256 / 4);

    for (int l = 0; l < 6; l++) {
        int fin = dims[l].fin, hid = dims[l].hid, fout = dims[l].fout;
        int HD = NH * hid;
        int hs = (hid == 128) ? 7 : (hid == 256) ? 8 : 9;
        const float* Wh = (const float*)d_in[2 + l * 4 + 0];
        const float* ah = (const float*)d_in[2 + l * 4 + 1];
        const float* Wo = (const float*)d_in[2 + l * 4 + 2];
        const float* ao = (const float*)d_in[2 + l * 4 + 3];

        // --- h = x @ Wh ---
        dim3 gt1(fin / 64, HD / 64);
        k_tsplit<<<gt1, 256, 0, stream>>>(Wh, bth, btl, fin, HD, hs);
        int skh = SKwh[l];
        if (skh > 1) hipMemsetAsync(hbuf, 0, (size_t)NN * HD * 4, stream);
        dim3 gg1(HD / 128, NN / 128, skh);
        k_mfma<<<gg1, 256, 0, stream>>>(xhi, xlo, bth, btl, hbuf, HD, fin, fin / skh, skh > 1);

        k_s<<<(NH * NN) / 4, 256, 0, stream>>>(hbuf, ah, s1, s2, NH, hid, HD);
        dim3 ga(NN, NH);
        k_agg<<<ga, 256, 0, stream>>>(hbuf, s1, s2, rp, ci, nullptr, ghi, glo, hid, HD, HD);

        // --- ho = hcat @ Wo ---
        dim3 gt2(HD / 64, fout / 64);
        k_tsplit<<<gt2, 256, 0, stream>>>(Wo, bth, btl, HD, fout, -1);
        int sko = SKwo[l];
        hipMemsetAsync(hob, 0, (size_t)NN * fout * 4, stream);
        dim3 gg2(fout / 128, NN / 128, sko);
        k_mfma<<<gg2, 256, 0, stream>>>(ghi, glo, bth, btl, hob, fout, HD, HD / sko, 1);

        k_s<<<NN / 4, 256, 0, stream>>>(hob, ao, t1, t2, 1, fout, fout);
        float* outF = (l == 5) ? (float*)d_out : nullptr;
        k_agg<<<dim3(NN, 1), 256, 0, stream>>>(hob, t1, t2, rp, ci, outF, xhi, xlo, fout, fout, fout);
    }
}

// Round 4
// 772.607 us; speedup vs baseline: 2.2121x; 1.0970x over previous
//
#include <hip/hip_runtime.h>
#include <hip/hip_bf16.h>
#include <math.h>

#define NN 2048          // n_nodes
#define NH 8             // heads
#define LRALPHA 0.2f
#define CHUNK 256        // neighbors per online-softmax chunk

typedef short bf16x8 __attribute__((ext_vector_type(8)));
typedef float f32x4  __attribute__((ext_vector_type(4)));

static __device__ __forceinline__ float lrelu(float x){ return x > 0.f ? x : LRALPHA * x; }
static __device__ __forceinline__ float elu(float x){ return x > 0.f ? x : expm1f(x); }

// bf16 round-to-nearest-even via bit ops (finite inputs)
static __device__ __forceinline__ unsigned short f2bf(float v){
    unsigned u = __float_as_uint(v);
    unsigned r = (u + 0x7fffu + ((u >> 16) & 1u)) >> 16;
    return (unsigned short)r;
}
static __device__ __forceinline__ float bf2f(unsigned short b){
    return __uint_as_float(((unsigned)b) << 16);
}

static __device__ __forceinline__ void gload16(const void* g, void* l){
    __builtin_amdgcn_global_load_lds((const __attribute__((address_space(1))) void*)g,
                                     (__attribute__((address_space(3))) void*)l, 16, 0, 0);
}

// ---------------- CSR build (deterministic, sorted by column) ----------------
__global__ void k_count(const float* __restrict__ adj, int* __restrict__ deg) {
    int gw   = (blockIdx.x * blockDim.x + threadIdx.x) >> 6;
    int lane = threadIdx.x & 63;
    if (gw >= NN) return;
    const float* row = adj + (size_t)gw * NN;
    int cnt = 0;
    for (int j = lane; j < NN; j += 64) cnt += (row[j] > 0.f) ? 1 : 0;
    #pragma unroll
    for (int off = 32; off; off >>= 1) cnt += __shfl_down(cnt, off);
    if (lane == 0) deg[gw] = cnt;
}

__global__ void k_scan(const int* __restrict__ deg, int* __restrict__ rp) {
    __shared__ int a[NN], b[NN];
    int t = threadIdx.x;                       // 1024 threads
    for (int i = t; i < NN; i += 1024) a[i] = deg[i];
    __syncthreads();
    int* src = a; int* dst = b;
    for (int off = 1; off < NN; off <<= 1) {
        for (int i = t; i < NN; i += 1024)
            dst[i] = src[i] + (i >= off ? src[i - off] : 0);
        __syncthreads();
        int* tmp = src; src = dst; dst = tmp;
    }
    for (int i = t; i < NN; i += 1024) rp[i + 1] = src[i];
    if (t == 0) rp[0] = 0;
}

__global__ void k_fill(const float* __restrict__ adj, const int* __restrict__ rp,
                       int* __restrict__ ci) {
    int gw   = (blockIdx.x * blockDim.x + threadIdx.x) >> 6;
    int lane = threadIdx.x & 63;
    if (gw >= NN) return;
    const float* row = adj + (size_t)gw * NN;
    int base = rp[gw];
    for (int j0 = 0; j0 < NN; j0 += 64) {
        bool v = row[j0 + lane] > 0.f;
        unsigned long long m = __ballot(v);
        int pos = __popcll(m & ((1ULL << lane) - 1ULL));
        if (v) ci[base + pos] = j0 + lane;
        base += __popcll(m);
    }
}

// ---------------- split fp32 -> bf16 hi/lo (elementwise, for input x) ----------------
__global__ void k_split(const float* __restrict__ src, unsigned short* __restrict__ hi,
                        unsigned short* __restrict__ lo, int n4) {
    int i = blockIdx.x * 256 + threadIdx.x;
    if (i >= n4) return;
    float4 v = ((const float4*)src)[i];
    ushort4 h, l;
    h.x = f2bf(v.x); l.x = f2bf(v.x - bf2f(h.x));
    h.y = f2bf(v.y); l.y = f2bf(v.y - bf2f(h.y));
    h.z = f2bf(v.z); l.z = f2bf(v.z - bf2f(h.z));
    h.w = f2bf(v.w); l.w = f2bf(v.w - bf2f(h.w));
    ((ushort4*)hi)[i] = h;
    ((ushort4*)lo)[i] = l;
}

// ------- weight transpose + split: B[k][c] (fp32) -> Bt_hi/lo [c][k] (bf16) -------
__global__ __launch_bounds__(256) void k_tsplit(const float* __restrict__ B,
        unsigned short* __restrict__ bth, unsigned short* __restrict__ btl,
        int K, int Nc, int hs) {
    __shared__ float t[64][65];
    int tid = threadIdx.x;
    int kb = blockIdx.x * 64, cb = blockIdx.y * 64;
    #pragma unroll
    for (int i = 0; i < 16; i++) {
        int idx = i * 256 + tid;
        int kk = idx >> 6, cc = idx & 63;
        int c = cb + cc, k = kb + kk;
        float v;
        if (hs < 0) v = B[(size_t)k * Nc + c];
        else {
            int hid = 1 << hs; int head = c >> hs; int d = c & (hid - 1);
            v = B[((size_t)head * K + k) * hid + d];
        }
        t[kk][cc] = v;
    }
    __syncthreads();
    #pragma unroll
    for (int i = 0; i < 16; i++) {
        int idx = i * 256 + tid;
        int cc = idx >> 6, kk = idx & 63;
        float v = t[kk][cc];
        unsigned short h = f2bf(v);
        size_t o = (size_t)(cb + cc) * K + kb + kk;
        bth[o] = h;
        btl[o] = f2bf(v - bf2f(h));
    }
}

// ---------------- split-bf16 MFMA GEMM (unchanged) ----------------
__global__ __launch_bounds__(256) void k_mfma(
    const unsigned short* __restrict__ Ah, const unsigned short* __restrict__ Al,
    const unsigned short* __restrict__ Bh, const unsigned short* __restrict__ Bl,
    float* __restrict__ C, int Nc, int K, int Kc, int atom)
{
    __shared__ unsigned short lds[16384];
    int tid = threadIdx.x, lane = tid & 63, w = tid >> 6;
    int m0 = blockIdx.y * 128, n0 = blockIdx.x * 128;
    int kbeg = blockIdx.z * Kc;

    int sA = tid, sB = 256 + tid;
    int ra = sA >> 2, ga = ((sA & 3) - (ra >> 1)) & 3;
    int rb = sB >> 2, gb = ((sB & 3) - (rb >> 1)) & 3;
    const unsigned short* pAh0 = Ah + (size_t)(m0 + ra) * K + kbeg + ga * 8;
    const unsigned short* pAh1 = Ah + (size_t)(m0 + rb) * K + kbeg + gb * 8;
    const unsigned short* pAl0 = Al + (size_t)(m0 + ra) * K + kbeg + ga * 8;
    const unsigned short* pAl1 = Al + (size_t)(m0 + rb) * K + kbeg + gb * 8;
    const unsigned short* pBh0 = Bh + (size_t)(n0 + ra) * K + kbeg + ga * 8;
    const unsigned short* pBh1 = Bh + (size_t)(n0 + rb) * K + kbeg + gb * 8;
    const unsigned short* pBl0 = Bl + (size_t)(n0 + ra) * K + kbeg + ga * 8;
    const unsigned short* pBl1 = Bl + (size_t)(n0 + rb) * K + kbeg + gb * 8;
    unsigned short* d0 = &lds[(w * 64) * 8];
    unsigned short* d1 = &lds[(256 + w * 64) * 8];

    int wr = w >> 1, wc = w & 1;
    int offA[4], offB[4];
    #pragma unroll
    for (int m = 0; m < 4; m++) {
        int row = wr * 64 + m * 16 + (lane & 15); int g = lane >> 4;
        offA[m] = (row * 4 + ((g + (row >> 1)) & 3)) * 8;
    }
    #pragma unroll
    for (int n = 0; n < 4; n++) {
        int row = wc * 64 + n * 16 + (lane & 15); int g = lane >> 4;
        offB[n] = (row * 4 + ((g + (row >> 1)) & 3)) * 8;
    }

    f32x4 acc[4][4];
    #pragma unroll
    for (int m = 0; m < 4; m++)
        #pragma unroll
        for (int n = 0; n < 4; n++) acc[m][n] = (f32x4){0.f, 0.f, 0.f, 0.f};

    int nk = Kc >> 5;
    for (int ks = 0; ks < nk; ks++) {
        gload16(pAh0, d0);          gload16(pAh1, d1);
        gload16(pAl0, d0 + 4096);   gload16(pAl1, d1 + 4096);
        gload16(pBh0, d0 + 8192);   gload16(pBh1, d1 + 8192);
        gload16(pBl0, d0 + 12288);  gload16(pBl1, d1 + 12288);
        pAh0 += 32; pAh1 += 32; pAl0 += 32; pAl1 += 32;
        pBh0 += 32; pBh1 += 32; pBl0 += 32; pBl1 += 32;
        __syncthreads();
        bf16x8 ah[4], al[4], bh[4], bl[4];
        #pragma unroll
        for (int m = 0; m < 4; m++) {
            ah[m] = *(const bf16x8*)&lds[offA[m]];
            al[m] = *(const bf16x8*)&lds[4096 + offA[m]];
        }
        #pragma unroll
        for (int n = 0; n < 4; n++) {
            bh[n] = *(const bf16x8*)&lds[8192 + offB[n]];
            bl[n] = *(const bf16x8*)&lds[12288 + offB[n]];
        }
        #pragma unroll
        for (int m = 0; m < 4; m++)
            #pragma unroll
            for (int n = 0; n < 4; n++) {
                acc[m][n] = __builtin_amdgcn_mfma_f32_16x16x32_bf16(ah[m], bh[n], acc[m][n], 0, 0, 0);
                acc[m][n] = __builtin_amdgcn_mfma_f32_16x16x32_bf16(al[m], bh[n], acc[m][n], 0, 0, 0);
                acc[m][n] = __builtin_amdgcn_mfma_f32_16x16x32_bf16(ah[m], bl[n], acc[m][n], 0, 0, 0);
            }
        __syncthreads();
    }

    #pragma unroll
    for (int m = 0; m < 4; m++)
        #pragma unroll
        for (int n = 0; n < 4; n++) {
            int row = m0 + wr * 64 + m * 16 + (lane >> 4) * 4;
            int col = n0 + wc * 64 + n * 16 + (lane & 15);
            #pragma unroll
            for (int r = 0; r < 4; r++) {
                float v = acc[m][n][r];
                float* p = &C[(size_t)(row + r) * Nc + col];
                if (atom) atomicAdd(p, v); else *p = v;
            }
        }
}

// ---------------- s1/s2 (or t1/t2): one wave per (head, node) ----------------
__global__ void k_s(const float* __restrict__ h, const float* __restrict__ a,
                    float* __restrict__ s1, float* __restrict__ s2,
                    int Hn, int hid, int HD)
{
    int gw   = (blockIdx.x * blockDim.x + threadIdx.x) >> 6;
    int lane = threadIdx.x & 63;
    if (gw >= Hn * NN) return;
    int head = gw >> 11;
    int i    = gw & (NN - 1);
    const float* hr = h + (size_t)i * HD + head * hid;
    const float* a1 = a + (size_t)head * 2 * hid;
    const float* a2 = a1 + hid;
    float acc1 = 0.f, acc2 = 0.f;
    for (int d = lane; d < hid; d += 64) {
        float v = hr[d];
        acc1 += v * a1[d];
        acc2 += v * a2[d];
    }
    #pragma unroll
    for (int off = 32; off; off >>= 1) {
        acc1 += __shfl_down(acc1, off);
        acc2 += __shfl_down(acc2, off);
    }
    if (lane == 0) { s1[gw] = acc1; s2[gw] = acc2; }
}

// ------------- sparse masked softmax + aggregation -------------
// 1-D grid; head = blk & headMask, node = blk >> nodeShift. With NH=8 and the
// dispatcher's round-robin blockIdx->XCD mapping, XCD k serves only head k, so
// the per-head 4MB h-slice stays resident in that XCD's L2 (gathers = L2 hits).
__global__ __launch_bounds__(256) void k_agg(
    const float* __restrict__ hsrc, const float* __restrict__ s1, const float* __restrict__ s2,
    const int* __restrict__ rp, const int* __restrict__ ci,
    float* __restrict__ outF, unsigned short* __restrict__ outH, unsigned short* __restrict__ outL,
    int hid, int HD, int HDout, int headMask, int nodeShift)
{
    __shared__ float  w[CHUNK];
    __shared__ int    cols[CHUNK];
    __shared__ float4 redbuf[256];
    __shared__ float  red[8];

    int blk  = blockIdx.x;
    int head = blk & headMask;
    int i    = blk >> nodeShift;
    int tid = threadIdx.x, lane = tid & 63, wid = tid >> 6;
    int base = rp[i], deg = rp[i + 1] - base;
    float s1i = s1[head * NN + i];
    const float* s2h = s2 + head * NN;

    int C4  = hid >> 2;           // float4 columns per head slice
    int G   = 256 / C4;           // neighbor groups
    int col = tid % C4;
    int grp = tid / C4;
    bool active = grp < G;

    const float4* h4 = (const float4*)hsrc;
    int hoff4 = (head * hid) >> 2;
    int ld4   = HD >> 2;

    float m_run = -1e30f, s_run = 0.f;
    float4 acc = make_float4(0.f, 0.f, 0.f, 0.f);

    for (int k0 = 0; k0 < deg; k0 += CHUNK) {
        int n = min(CHUNK, deg - k0);
        __syncthreads();                         // protect w/cols/red reuse
        // scores + local max
        float m = -1e30f;
        for (int k = tid; k < n; k += 256) {
            int j = ci[base + k0 + k];
            float e = lrelu(s1i + s2h[j]);
            cols[k] = j; w[k] = e;
            m = fmaxf(m, e);
        }
        #pragma unroll
        for (int off = 32; off; off >>= 1) m = fmaxf(m, __shfl_down(m, off));
        if (lane == 0) red[wid] = m;
        __syncthreads();
        float bm = fmaxf(fmaxf(red[0], red[1]), fmaxf(red[2], red[3]));
        float m2 = fmaxf(m_run, bm);

        // exp + local sum
        float sum = 0.f;
        for (int k = tid; k < n; k += 256) {
            float wv = expf(w[k] - m2);
            w[k] = wv;
            sum += wv;
        }
        #pragma unroll
        for (int off = 32; off; off >>= 1) sum += __shfl_down(sum, off);
        if (lane == 0) red[4 + wid] = sum;
        __syncthreads();                         // also covers w[] writes
        float csum = red[4] + red[5] + red[6] + red[7];

        float scale = expf(m_run - m2);          // exp(-inf)=0 first time
        s_run = s_run * scale + csum;
        acc.x *= scale; acc.y *= scale; acc.z *= scale; acc.w *= scale;
        m_run = m2;

        // gather: group grp takes neighbors k = grp, grp+G, ... (2-way unrolled)
        if (active) {
            float4 acc2 = make_float4(0.f, 0.f, 0.f, 0.f);
            int k = grp;
            for (; k + G < n; k += 2 * G) {
                float w0 = w[k], w1 = w[k + G];
                float4 h0 = h4[(size_t)cols[k]     * ld4 + hoff4 + col];
                float4 h1 = h4[(size_t)cols[k + G] * ld4 + hoff4 + col];
                acc.x  += w0 * h0.x; acc.y  += w0 * h0.y; acc.z  += w0 * h0.z; acc.w  += w0 * h0.w;
                acc2.x += w1 * h1.x; acc2.y += w1 * h1.y; acc2.z += w1 * h1.z; acc2.w += w1 * h1.w;
            }
            if (k < n) {
                float w0 = w[k];
                float4 h0 = h4[(size_t)cols[k] * ld4 + hoff4 + col];
                acc.x += w0 * h0.x; acc.y += w0 * h0.y; acc.z += w0 * h0.z; acc.w += w0 * h0.w;
            }
            acc.x += acc2.x; acc.y += acc2.y; acc.z += acc2.z; acc.w += acc2.w;
        }
    }

    // reduce acc across groups
    redbuf[tid] = acc;
    __syncthreads();
    if (grp == 0) {
        for (int g = 1; g < G; g++) {
            float4 o = redbuf[g * C4 + col];
            acc.x += o.x; acc.y += o.y; acc.z += o.z; acc.w += o.w;
        }
        float inv = 1.f / s_run;
        float4 val;
        val.x = elu(acc.x * inv); val.y = elu(acc.y * inv);
        val.z = elu(acc.z * inv); val.w = elu(acc.w * inv);
        size_t o4 = ((size_t)i * HDout + head * hid) / 4 + col;
        if (outF) ((float4*)outF)[o4] = val;
        ushort4 h, l;
        h.x = f2bf(val.x); l.x = f2bf(val.x - bf2f(h.x));
        h.y = f2bf(val.y); l.y = f2bf(val.y - bf2f(h.y));
        h.z = f2bf(val.z); l.z = f2bf(val.z - bf2f(h.z));
        h.w = f2bf(val.w); l.w = f2bf(val.w - bf2f(h.w));
        ((ushort4*)outH)[o4] = h;
        ((ushort4*)outL)[o4] = l;
    }
}

// ---------------- host driver ----------------
extern "C" void kernel_launch(void* const* d_in, const int* in_sizes, int n_in,
                              void* d_out, int out_size, void* d_ws, size_t ws_size,
                              hipStream_t stream)
{
    const float* x   = (const float*)d_in[0];
    const float* adj = (const float*)d_in[1];
    struct L { int fin, hid, fout; };
    const L dims[6] = {{256,128,128},{128,256,256},{256,512,384},
                       {384,512,256},{256,256,128},{128,128,256}};
    const int SKwh[6] = {2, 1, 1, 1, 1, 2};
    const int SKwo[6] = {16, 8, 8, 8, 16, 8};

    char* ws = (char*)d_ws;
    size_t off = 0;
    auto alloc = [&](size_t bytes) -> void* {
        void* p = ws + off;
        off = (off + bytes + 255) & ~(size_t)255;
        return p;
    };
    int*   rp   = (int*)alloc((NN + 1) * sizeof(int));
    int*   deg  = (int*)alloc(NN * sizeof(int));
    int*   ci   = (int*)alloc((size_t)(1 << 20) * sizeof(int));
    float* hbuf = (float*)alloc((size_t)NN * 4096 * sizeof(float));
    unsigned short* ghi = (unsigned short*)alloc((size_t)NN * 4096 * 2);
    unsigned short* glo = (unsigned short*)alloc((size_t)NN * 4096 * 2);
    float* hob = (float*)alloc((size_t)NN * 512 * sizeof(float));
    unsigned short* xhi = (unsigned short*)alloc((size_t)NN * 512 * 2);
    unsigned short* xlo = (unsigned short*)alloc((size_t)NN * 512 * 2);
    unsigned short* bth = (unsigned short*)alloc((size_t)4096 * 512 * 2);
    unsigned short* btl = (unsigned short*)alloc((size_t)4096 * 512 * 2);
    float* s1 = (float*)alloc((size_t)NH * NN * sizeof(float));
    float* s2 = (float*)alloc((size_t)NH * NN * sizeof(float));
    float* t1 = (float*)alloc(NN * sizeof(float));
    float* t2 = (float*)alloc(NN * sizeof(float));

    k_count<<<NN / 4, 256, 0, stream>>>(adj, deg);
    k_scan <<<1, 1024, 0, stream>>>(deg, rp);
    k_fill <<<NN / 4, 256, 0, stream>>>(adj, rp, ci);

    k_split<<<(NN * 256 / 4 + 255) / 256, 256, 0, stream>>>(x, xhi, xlo, NN * 256 / 4);

    for (int l = 0; l < 6; l++) {
        int fin = dims[l].fin, hid = dims[l].hid, fout = dims[l].fout;
        int HD = NH * hid;
        int hs = (hid == 128) ? 7 : (hid == 256) ? 8 : 9;
        const float* Wh = (const float*)d_in[2 + l * 4 + 0];
        const float* ah = (const float*)d_in[2 + l * 4 + 1];
        const float* Wo = (const float*)d_in[2 + l * 4 + 2];
        const float* ao = (const float*)d_in[2 + l * 4 + 3];

        // --- h = x @ Wh ---
        dim3 gt1(fin / 64, HD / 64);
        k_tsplit<<<gt1, 256, 0, stream>>>(Wh, bth, btl, fin, HD, hs);
        int skh = SKwh[l];
        if (skh > 1) hipMemsetAsync(hbuf, 0, (size_t)NN * HD * 4, stream);
        dim3 gg1(HD / 128, NN / 128, skh);
        k_mfma<<<gg1, 256, 0, stream>>>(xhi, xlo, bth, btl, hbuf, HD, fin, fin / skh, skh > 1);

        k_s<<<(NH * NN) / 4, 256, 0, stream>>>(hbuf, ah, s1, s2, NH, hid, HD);
        // 1-D grid, head = blk & 7 -> XCD-head affinity
        k_agg<<<NN * NH, 256, 0, stream>>>(hbuf, s1, s2, rp, ci, nullptr, ghi, glo,
                                           hid, HD, HD, NH - 1, 3);

        // --- ho = hcat @ Wo ---
        dim3 gt2(HD / 64, fout / 64);
        k_tsplit<<<gt2, 256, 0, stream>>>(Wo, bth, btl, HD, fout, -1);
        int sko = SKwo[l];
        hipMemsetAsync(hob, 0, (size_t)NN * fout * 4, stream);
        dim3 gg2(fout / 128, NN / 128, sko);
        k_mfma<<<gg2, 256, 0, stream>>>(ghi, glo, bth, btl, hob, fout, HD, HD / sko, 1);

        k_s<<<NN / 4, 256, 0, stream>>>(hob, ao, t1, t2, 1, fout, fout);
        float* outF = (l == 5) ? (float*)d_out : nullptr;
        k_agg<<<NN, 256, 0, stream>>>(hob, t1, t2, rp, ci, outF, xhi, xlo,
                                      fout, fout, fout, 0, 0);
    }
}

// Round 5
// 737.944 us; speedup vs baseline: 2.3160x; 1.0470x over previous
//
#include <hip/hip_runtime.h>
#include <hip/hip_bf16.h>
#include <math.h>

#define NN 2048          // n_nodes
#define NH 8             // heads
#define LRALPHA 0.2f
#define CHUNK 256        // neighbors per online-softmax chunk

typedef short bf16x8 __attribute__((ext_vector_type(8)));
typedef float f32x4  __attribute__((ext_vector_type(4)));

static __device__ __forceinline__ float lrelu(float x){ return x > 0.f ? x : LRALPHA * x; }
static __device__ __forceinline__ float elu(float x){ return x > 0.f ? x : expm1f(x); }

// bf16 round-to-nearest-even via bit ops (finite inputs)
static __device__ __forceinline__ unsigned short f2bf(float v){
    unsigned u = __float_as_uint(v);
    unsigned r = (u + 0x7fffu + ((u >> 16) & 1u)) >> 16;
    return (unsigned short)r;
}
static __device__ __forceinline__ float bf2f(unsigned short b){
    return __uint_as_float(((unsigned)b) << 16);
}

static __device__ __forceinline__ void gload16(const void* g, void* l){
    __builtin_amdgcn_global_load_lds((const __attribute__((address_space(1))) void*)g,
                                     (__attribute__((address_space(3))) void*)l, 16, 0, 0);
}

// ---------------- CSR build (deterministic, sorted by column) ----------------
__global__ void k_count(const float* __restrict__ adj, int* __restrict__ deg) {
    int gw   = (blockIdx.x * blockDim.x + threadIdx.x) >> 6;
    int lane = threadIdx.x & 63;
    if (gw >= NN) return;
    const float* row = adj + (size_t)gw * NN;
    int cnt = 0;
    for (int j = lane; j < NN; j += 64) cnt += (row[j] > 0.f) ? 1 : 0;
    #pragma unroll
    for (int off = 32; off; off >>= 1) cnt += __shfl_down(cnt, off);
    if (lane == 0) deg[gw] = cnt;
}

__global__ void k_scan(const int* __restrict__ deg, int* __restrict__ rp) {
    __shared__ int a[NN], b[NN];
    int t = threadIdx.x;                       // 1024 threads
    for (int i = t; i < NN; i += 1024) a[i] = deg[i];
    __syncthreads();
    int* src = a; int* dst = b;
    for (int off = 1; off < NN; off <<= 1) {
        for (int i = t; i < NN; i += 1024)
            dst[i] = src[i] + (i >= off ? src[i - off] : 0);
        __syncthreads();
        int* tmp = src; src = dst; dst = tmp;
    }
    for (int i = t; i < NN; i += 1024) rp[i + 1] = src[i];
    if (t == 0) rp[0] = 0;
}

__global__ void k_fill(const float* __restrict__ adj, const int* __restrict__ rp,
                       int* __restrict__ ci) {
    int gw   = (blockIdx.x * blockDim.x + threadIdx.x) >> 6;
    int lane = threadIdx.x & 63;
    if (gw >= NN) return;
    const float* row = adj + (size_t)gw * NN;
    int base = rp[gw];
    for (int j0 = 0; j0 < NN; j0 += 64) {
        bool v = row[j0 + lane] > 0.f;
        unsigned long long m = __ballot(v);
        int pos = __popcll(m & ((1ULL << lane) - 1ULL));
        if (v) ci[base + pos] = j0 + lane;
        base += __popcll(m);
    }
}

// ---------------- split fp32 -> bf16 hi/lo (elementwise, for input x) ----------------
__global__ void k_split(const float* __restrict__ src, unsigned short* __restrict__ hi,
                        unsigned short* __restrict__ lo, int n4) {
    int i = blockIdx.x * 256 + threadIdx.x;
    if (i >= n4) return;
    float4 v = ((const float4*)src)[i];
    ushort4 h, l;
    h.x = f2bf(v.x); l.x = f2bf(v.x - bf2f(h.x));
    h.y = f2bf(v.y); l.y = f2bf(v.y - bf2f(h.y));
    h.z = f2bf(v.z); l.z = f2bf(v.z - bf2f(h.z));
    h.w = f2bf(v.w); l.w = f2bf(v.w - bf2f(h.w));
    ((ushort4*)hi)[i] = h;
    ((ushort4*)lo)[i] = l;
}

// ------- ALL weight transposes+splits in ONE launch (weights depend only on inputs) ----
// Entry s: B[k][c] fp32 -> bh/bl [c][k] bf16.  hs<0: plain [K][Nc]; hs>=0: Wh head layout.
struct TSDesc {
    const float* B[12];
    unsigned short* bh[12];
    unsigned short* bl[12];
    int K[12], Nc[12], hs[12];
    int start[13];
};

__global__ __launch_bounds__(256) void k_tsplit_all(TSDesc d) {
    __shared__ float t[64][65];
    int b = blockIdx.x;
    int s = 0;
    while (b >= d.start[s + 1]) s++;
    int lb = b - d.start[s];
    int K = d.K[s], Nc = d.Nc[s], hs = d.hs[s];
    int tilesX = K >> 6;
    int kb = (lb % tilesX) * 64, cb = (lb / tilesX) * 64;
    const float* B = d.B[s];
    unsigned short* bth = d.bh[s];
    unsigned short* btl = d.bl[s];

    int tid = threadIdx.x;
    #pragma unroll
    for (int i = 0; i < 16; i++) {
        int idx = i * 256 + tid;
        int kk = idx >> 6, cc = idx & 63;
        int c = cb + cc, k = kb + kk;
        float v;
        if (hs < 0) v = B[(size_t)k * Nc + c];
        else {
            int hid = 1 << hs; int head = c >> hs; int dd = c & (hid - 1);
            v = B[((size_t)head * K + k) * hid + dd];
        }
        t[kk][cc] = v;
    }
    __syncthreads();
    #pragma unroll
    for (int i = 0; i < 16; i++) {
        int idx = i * 256 + tid;
        int cc = idx >> 6, kk = idx & 63;
        float v = t[kk][cc];
        unsigned short h = f2bf(v);
        size_t o = (size_t)(cb + cc) * K + kb + kk;
        bth[o] = h;
        btl[o] = f2bf(v - bf2f(h));
    }
}

// ---------------- split-bf16 MFMA GEMM with fused attention-score epilogue --------
// C[M][Nc] (+)= A@Bt^T.  Fused: sg1[head*NN+row] += sum_d C_partial[row,d]*av[d],
// sg2 likewise with av[d+aoff]  (linear in C => split-K safe).
__global__ __launch_bounds__(256) void k_mfma(
    const unsigned short* __restrict__ Ah, const unsigned short* __restrict__ Al,
    const unsigned short* __restrict__ Bh, const unsigned short* __restrict__ Bl,
    float* __restrict__ C, int Nc, int K, int Kc, int atom,
    const float* __restrict__ avec, float* __restrict__ sg1, float* __restrict__ sg2,
    int hs, int aoff)
{
    __shared__ unsigned short lds[16384];
    int tid = threadIdx.x, lane = tid & 63, w = tid >> 6;
    int m0 = blockIdx.y * 128, n0 = blockIdx.x * 128;
    int kbeg = blockIdx.z * Kc;

    int sA = tid, sB = 256 + tid;
    int ra = sA >> 2, ga = ((sA & 3) - (ra >> 1)) & 3;
    int rb = sB >> 2, gb = ((sB & 3) - (rb >> 1)) & 3;
    const unsigned short* pAh0 = Ah + (size_t)(m0 + ra) * K + kbeg + ga * 8;
    const unsigned short* pAh1 = Ah + (size_t)(m0 + rb) * K + kbeg + gb * 8;
    const unsigned short* pAl0 = Al + (size_t)(m0 + ra) * K + kbeg + ga * 8;
    const unsigned short* pAl1 = Al + (size_t)(m0 + rb) * K + kbeg + gb * 8;
    const unsigned short* pBh0 = Bh + (size_t)(n0 + ra) * K + kbeg + ga * 8;
    const unsigned short* pBh1 = Bh + (size_t)(n0 + rb) * K + kbeg + gb * 8;
    const unsigned short* pBl0 = Bl + (size_t)(n0 + ra) * K + kbeg + ga * 8;
    const unsigned short* pBl1 = Bl + (size_t)(n0 + rb) * K + kbeg + gb * 8;
    unsigned short* d0 = &lds[(w * 64) * 8];
    unsigned short* d1 = &lds[(256 + w * 64) * 8];

    int wr = w >> 1, wc = w & 1;
    int offA[4], offB[4];
    #pragma unroll
    for (int m = 0; m < 4; m++) {
        int row = wr * 64 + m * 16 + (lane & 15); int g = lane >> 4;
        offA[m] = (row * 4 + ((g + (row >> 1)) & 3)) * 8;
    }
    #pragma unroll
    for (int n = 0; n < 4; n++) {
        int row = wc * 64 + n * 16 + (lane & 15); int g = lane >> 4;
        offB[n] = (row * 4 + ((g + (row >> 1)) & 3)) * 8;
    }

    f32x4 acc[4][4];
    #pragma unroll
    for (int m = 0; m < 4; m++)
        #pragma unroll
        for (int n = 0; n < 4; n++) acc[m][n] = (f32x4){0.f, 0.f, 0.f, 0.f};

    int nk = Kc >> 5;
    for (int ks = 0; ks < nk; ks++) {
        gload16(pAh0, d0);          gload16(pAh1, d1);
        gload16(pAl0, d0 + 4096);   gload16(pAl1, d1 + 4096);
        gload16(pBh0, d0 + 8192);   gload16(pBh1, d1 + 8192);
        gload16(pBl0, d0 + 12288);  gload16(pBl1, d1 + 12288);
        pAh0 += 32; pAh1 += 32; pAl0 += 32; pAl1 += 32;
        pBh0 += 32; pBh1 += 32; pBl0 += 32; pBl1 += 32;
        __syncthreads();
        bf16x8 ah[4], al[4], bh[4], bl[4];
        #pragma unroll
        for (int m = 0; m < 4; m++) {
            ah[m] = *(const bf16x8*)&lds[offA[m]];
            al[m] = *(const bf16x8*)&lds[4096 + offA[m]];
        }
        #pragma unroll
        for (int n = 0; n < 4; n++) {
            bh[n] = *(const bf16x8*)&lds[8192 + offB[n]];
            bl[n] = *(const bf16x8*)&lds[12288 + offB[n]];
        }
        #pragma unroll
        for (int m = 0; m < 4; m++)
            #pragma unroll
            for (int n = 0; n < 4; n++) {
                acc[m][n] = __builtin_amdgcn_mfma_f32_16x16x32_bf16(ah[m], bh[n], acc[m][n], 0, 0, 0);
                acc[m][n] = __builtin_amdgcn_mfma_f32_16x16x32_bf16(al[m], bh[n], acc[m][n], 0, 0, 0);
                acc[m][n] = __builtin_amdgcn_mfma_f32_16x16x32_bf16(ah[m], bl[n], acc[m][n], 0, 0, 0);
            }
        __syncthreads();
    }

    // C write
    #pragma unroll
    for (int m = 0; m < 4; m++)
        #pragma unroll
        for (int n = 0; n < 4; n++) {
            int row = m0 + wr * 64 + m * 16 + (lane >> 4) * 4;
            int col = n0 + wc * 64 + n * 16 + (lane & 15);
            #pragma unroll
            for (int r = 0; r < 4; r++) {
                float v = acc[m][n][r];
                float* p = &C[(size_t)(row + r) * Nc + col];
                if (atom) atomicAdd(p, v); else *p = v;
            }
        }

    // fused s1/s2 epilogue (tile is always within a single head: hid>=128, tiles 128-aligned)
    int head = (hs >= 0) ? (n0 >> hs) : 0;
    const float* ab = avec + head * 2 * aoff;
    float av1[4], av2[4];
    int colbase = n0 + wc * 64 + (lane & 15);
    #pragma unroll
    for (int n = 0; n < 4; n++) {
        int c = colbase + n * 16;
        int dd = (hs >= 0) ? (c & (aoff - 1)) : c;
        av1[n] = ab[dd];
        av2[n] = ab[dd + aoff];
    }
    #pragma unroll
    for (int m = 0; m < 4; m++)
        #pragma unroll
        for (int r = 0; r < 4; r++) {
            float p1 = 0.f, p2 = 0.f;
            #pragma unroll
            for (int n = 0; n < 4; n++) {
                float v = acc[m][n][r];
                p1 += v * av1[n];
                p2 += v * av2[n];
            }
            #pragma unroll
            for (int o = 1; o < 16; o <<= 1) {
                p1 += __shfl_xor(p1, o);
                p2 += __shfl_xor(p2, o);
            }
            if ((lane & 15) == 0) {
                int row = m0 + wr * 64 + m * 16 + (lane >> 4) * 4 + r;
                atomicAdd(&sg1[head * NN + row], p1);
                atomicAdd(&sg2[head * NN + row], p2);
            }
        }
}

// ------------- sparse masked softmax + aggregation -------------
// 1-D grid; head = blk & headMask, node = blk >> nodeShift (XCD<->head affinity).
__global__ __launch_bounds__(256) void k_agg(
    const float* __restrict__ hsrc, const float* __restrict__ s1, const float* __restrict__ s2,
    const int* __restrict__ rp, const int* __restrict__ ci,
    float* __restrict__ outF, unsigned short* __restrict__ outH, unsigned short* __restrict__ outL,
    int hid, int HD, int HDout, int headMask, int nodeShift)
{
    __shared__ float  w[CHUNK];
    __shared__ unsigned cols[CHUNK];          // precomputed float4 offsets
    __shared__ float4 redbuf[256];
    __shared__ float  red[8];

    int blk  = blockIdx.x;
    int head = blk & headMask;
    int i    = blk >> nodeShift;
    int tid = threadIdx.x, lane = tid & 63, wid = tid >> 6;
    int base = rp[i], deg = rp[i + 1] - base;
    float s1i = s1[head * NN + i];
    const float* s2h = s2 + head * NN;

    int C4  = hid >> 2;           // float4 columns per head slice
    int G   = 256 / C4;           // neighbor groups
    int col = tid % C4;
    int grp = tid / C4;
    bool active = grp < G;

    const float4* h4 = (const float4*)hsrc;
    unsigned hoff4 = (head * hid) >> 2;
    unsigned ld4   = HD >> 2;

    float m_run = -1e30f, s_run = 0.f;
    float4 acc = make_float4(0.f, 0.f, 0.f, 0.f);

    for (int k0 = 0; k0 < deg; k0 += CHUNK) {
        int n = min(CHUNK, deg - k0);
        __syncthreads();                         // protect w/cols/red reuse
        // scores + local max; store precomputed gather offsets
        float m = -1e30f;
        for (int k = tid; k < n; k += 256) {
            int j = ci[base + k0 + k];
            float e = lrelu(s1i + s2h[j]);
            cols[k] = (unsigned)j * ld4 + hoff4;
            w[k] = e;
            m = fmaxf(m, e);
        }
        #pragma unroll
        for (int off = 32; off; off >>= 1) m = fmaxf(m, __shfl_down(m, off));
        if (lane == 0) red[wid] = m;
        __syncthreads();
        float bm = fmaxf(fmaxf(red[0], red[1]), fmaxf(red[2], red[3]));
        float m2 = fmaxf(m_run, bm);

        // exp + local sum
        float sum = 0.f;
        for (int k = tid; k < n; k += 256) {
            float wv = expf(w[k] - m2);
            w[k] = wv;
            sum += wv;
        }
        #pragma unroll
        for (int off = 32; off; off >>= 1) sum += __shfl_down(sum, off);
        if (lane == 0) red[4 + wid] = sum;
        __syncthreads();                         // also covers w[] writes
        float csum = red[4] + red[5] + red[6] + red[7];

        float scale = expf(m_run - m2);          // exp(-inf)=0 first time
        s_run = s_run * scale + csum;
        acc.x *= scale; acc.y *= scale; acc.z *= scale; acc.w *= scale;
        m_run = m2;

        // gather: group grp takes neighbors k = grp, grp+G, ... (4-way unrolled)
        if (active) {
            float4 q1 = make_float4(0,0,0,0), q2 = make_float4(0,0,0,0), q3 = make_float4(0,0,0,0);
            int k = grp;
            for (; k + 3 * G < n; k += 4 * G) {
                float w0 = w[k], w1 = w[k + G], w2 = w[k + 2 * G], w3 = w[k + 3 * G];
                float4 h0 = h4[cols[k]         + col];
                float4 h1 = h4[cols[k + G]     + col];
                float4 h2 = h4[cols[k + 2 * G] + col];
                float4 h3 = h4[cols[k + 3 * G] + col];
                acc.x += w0 * h0.x; acc.y += w0 * h0.y; acc.z += w0 * h0.z; acc.w += w0 * h0.w;
                q1.x  += w1 * h1.x; q1.y  += w1 * h1.y; q1.z  += w1 * h1.z; q1.w  += w1 * h1.w;
                q2.x  += w2 * h2.x; q2.y  += w2 * h2.y; q2.z  += w2 * h2.z; q2.w  += w2 * h2.w;
                q3.x  += w3 * h3.x; q3.y  += w3 * h3.y; q3.z  += w3 * h3.z; q3.w  += w3 * h3.w;
            }
            for (; k < n; k += G) {
                float w0 = w[k];
                float4 h0 = h4[cols[k] + col];
                acc.x += w0 * h0.x; acc.y += w0 * h0.y; acc.z += w0 * h0.z; acc.w += w0 * h0.w;
            }
            acc.x += q1.x + q2.x + q3.x; acc.y += q1.y + q2.y + q3.y;
            acc.z += q1.z + q2.z + q3.z; acc.w += q1.w + q2.w + q3.w;
        }
    }

    // reduce acc across groups
    redbuf[tid] = acc;
    __syncthreads();
    if (grp == 0) {
        for (int g = 1; g < G; g++) {
            float4 o = redbuf[g * C4 + col];
            acc.x += o.x; acc.y += o.y; acc.z += o.z; acc.w += o.w;
        }
        float inv = 1.f / s_run;
        float4 val;
        val.x = elu(acc.x * inv); val.y = elu(acc.y * inv);
        val.z = elu(acc.z * inv); val.w = elu(acc.w * inv);
        size_t o4 = ((size_t)i * HDout + head * hid) / 4 + col;
        if (outF) ((float4*)outF)[o4] = val;
        ushort4 h, l;
        h.x = f2bf(val.x); l.x = f2bf(val.x - bf2f(h.x));
        h.y = f2bf(val.y); l.y = f2bf(val.y - bf2f(h.y));
        h.z = f2bf(val.z); l.z = f2bf(val.z - bf2f(h.z));
        h.w = f2bf(val.w); l.w = f2bf(val.w - bf2f(h.w));
        ((ushort4*)outH)[o4] = h;
        ((ushort4*)outL)[o4] = l;
    }
}

// ---------------- host driver ----------------
extern "C" void kernel_launch(void* const* d_in, const int* in_sizes, int n_in,
                              void* d_out, int out_size, void* d_ws, size_t ws_size,
                              hipStream_t stream)
{
    const float* x   = (const float*)d_in[0];
    const float* adj = (const float*)d_in[1];
    struct L { int fin, hid, fout; };
    const L dims[6] = {{256,128,128},{128,256,256},{256,512,384},
                       {384,512,256},{256,256,128},{128,128,256}};
    const int SKwh[6] = {2, 1, 1, 1, 1, 2};
    const int SKwo[6] = {16, 8, 8, 8, 16, 8};

    char* ws = (char*)d_ws;
    size_t off = 0;
    auto alloc = [&](size_t bytes) -> void* {
        void* p = ws + off;
        off = (off + bytes + 255) & ~(size_t)255;
        return p;
    };
    int*   rp   = (int*)alloc((NN + 1) * sizeof(int));
    int*   deg  = (int*)alloc(NN * sizeof(int));
    int*   ci   = (int*)alloc((size_t)(1 << 20) * sizeof(int));
    float* hbuf = (float*)alloc((size_t)NN * 4096 * sizeof(float));
    unsigned short* ghi = (unsigned short*)alloc((size_t)NN * 4096 * 2);
    unsigned short* glo = (unsigned short*)alloc((size_t)NN * 4096 * 2);
    float* hob = (float*)alloc((size_t)NN * 512 * sizeof(float));
    unsigned short* xhi = (unsigned short*)alloc((size_t)NN * 512 * 2);
    unsigned short* xlo = (unsigned short*)alloc((size_t)NN * 512 * 2);
    // contiguous score buffers: s1, s2, t1, t2
    float* sbuf = (float*)alloc((size_t)(2 * NH * NN + 2 * NN) * sizeof(float));
    float* s1 = sbuf;
    float* s2 = sbuf + NH * NN;
    float* t1 = sbuf + 2 * NH * NN;
    float* t2 = t1 + NN;

    // persistent per-layer split weights
    unsigned short* whh[6]; unsigned short* whl[6];
    unsigned short* woh[6]; unsigned short* wol[6];
    TSDesc td;
    int nblk = 0;
    for (int l = 0; l < 6; l++) {
        int fin = dims[l].fin, hid = dims[l].hid, fout = dims[l].fout;
        int HD = NH * hid;
        size_t szWh = (size_t)fin * HD, szWo = (size_t)HD * fout;
        whh[l] = (unsigned short*)alloc(szWh * 2);
        whl[l] = (unsigned short*)alloc(szWh * 2);
        woh[l] = (unsigned short*)alloc(szWo * 2);
        wol[l] = (unsigned short*)alloc(szWo * 2);
        int hs = (hid == 128) ? 7 : (hid == 256) ? 8 : 9;
        // entry 2l: Wh
        td.B[2*l] = (const float*)d_in[2 + l * 4 + 0];
        td.bh[2*l] = whh[l]; td.bl[2*l] = whl[l];
        td.K[2*l] = fin; td.Nc[2*l] = HD; td.hs[2*l] = hs;
        td.start[2*l] = nblk; nblk += (fin / 64) * (HD / 64);
        // entry 2l+1: Wo
        td.B[2*l+1] = (const float*)d_in[2 + l * 4 + 2];
        td.bh[2*l+1] = woh[l]; td.bl[2*l+1] = wol[l];
        td.K[2*l+1] = HD; td.Nc[2*l+1] = fout; td.hs[2*l+1] = -1;
        td.start[2*l+1] = nblk; nblk += (HD / 64) * (fout / 64);
    }
    td.start[12] = nblk;

    // ---- front matter: CSR, x split, ALL weight splits ----
    k_count<<<NN / 4, 256, 0, stream>>>(adj, deg);
    k_scan <<<1, 1024, 0, stream>>>(deg, rp);
    k_fill <<<NN / 4, 256, 0, stream>>>(adj, rp, ci);
    k_split<<<(NN * 256 / 4 + 255) / 256, 256, 0, stream>>>(x, xhi, xlo, NN * 256 / 4);
    k_tsplit_all<<<nblk, 256, 0, stream>>>(td);

    for (int l = 0; l < 6; l++) {
        int fin = dims[l].fin, hid = dims[l].hid, fout = dims[l].fout;
        int HD = NH * hid;
        int hs = (hid == 128) ? 7 : (hid == 256) ? 8 : 9;
        const float* ah = (const float*)d_in[2 + l * 4 + 1];
        const float* ao = (const float*)d_in[2 + l * 4 + 3];

        // zero score accumulators (s1,s2,t1,t2 contiguous)
        hipMemsetAsync(sbuf, 0, (size_t)(2 * NH * NN + 2 * NN) * sizeof(float), stream);

        // --- h = x @ Wh  (+ fused s1/s2) ---
        int skh = SKwh[l];
        if (skh > 1) hipMemsetAsync(hbuf, 0, (size_t)NN * HD * 4, stream);
        dim3 gg1(HD / 128, NN / 128, skh);
        k_mfma<<<gg1, 256, 0, stream>>>(xhi, xlo, whh[l], whl[l], hbuf, HD, fin, fin / skh,
                                        skh > 1, ah, s1, s2, hs, hid);

        // per-head masked softmax aggregation (XCD-head affinity)
        k_agg<<<NN * NH, 256, 0, stream>>>(hbuf, s1, s2, rp, ci, nullptr, ghi, glo,
                                           hid, HD, HD, NH - 1, 3);

        // --- ho = hcat @ Wo  (+ fused t1/t2) ---
        int sko = SKwo[l];
        hipMemsetAsync(hob, 0, (size_t)NN * fout * 4, stream);
        dim3 gg2(fout / 128, NN / 128, sko);
        k_mfma<<<gg2, 256, 0, stream>>>(ghi, glo, woh[l], wol[l], hob, fout, HD, HD / sko,
                                        1, ao, t1, t2, -1, fout);

        float* outF = (l == 5) ? (float*)d_out : nullptr;
        k_agg<<<NN, 256, 0, stream>>>(hob, t1, t2, rp, ci, outF, xhi, xlo,
                                      fout, fout, fout, 0, 0);
    }
}

// Round 6
// 684.471 us; speedup vs baseline: 2.4969x; 1.0781x over previous
//
#include <hip/hip_runtime.h>
#include <hip/hip_bf16.h>
#include <math.h>

#define NN 2048          // n_nodes
#define NH 8             // heads
#define LRALPHA 0.2f
#define CHUNK 256        // neighbors per online-softmax chunk

typedef short bf16x8 __attribute__((ext_vector_type(8)));
typedef float f32x4  __attribute__((ext_vector_type(4)));

static __device__ __forceinline__ float lrelu(float x){ return x > 0.f ? x : LRALPHA * x; }
static __device__ __forceinline__ float elu(float x){ return x > 0.f ? x : expm1f(x); }

// bf16 round-to-nearest-even via bit ops (finite inputs)
static __device__ __forceinline__ unsigned short f2bf(float v){
    unsigned u = __float_as_uint(v);
    unsigned r = (u + 0x7fffu + ((u >> 16) & 1u)) >> 16;
    return (unsigned short)r;
}
static __device__ __forceinline__ float bf2f(unsigned short b){
    return __uint_as_float(((unsigned)b) << 16);
}
// bf16 pair unpack from packed u32 (little-endian: low half = even elem)
static __device__ __forceinline__ float blo(unsigned u){ return __uint_as_float(u << 16); }
static __device__ __forceinline__ float bhi(unsigned u){ return __uint_as_float(u & 0xffff0000u); }

static __device__ __forceinline__ void gload16(const void* g, void* l){
    __builtin_amdgcn_global_load_lds((const __attribute__((address_space(1))) void*)g,
                                     (__attribute__((address_space(3))) void*)l, 16, 0, 0);
}

// ---------------- CSR build (deterministic, sorted by column) ----------------
__global__ void k_count(const float* __restrict__ adj, int* __restrict__ deg) {
    int gw   = (blockIdx.x * blockDim.x + threadIdx.x) >> 6;
    int lane = threadIdx.x & 63;
    if (gw >= NN) return;
    const float* row = adj + (size_t)gw * NN;
    int cnt = 0;
    for (int j = lane; j < NN; j += 64) cnt += (row[j] > 0.f) ? 1 : 0;
    #pragma unroll
    for (int off = 32; off; off >>= 1) cnt += __shfl_down(cnt, off);
    if (lane == 0) deg[gw] = cnt;
}

__global__ void k_scan(const int* __restrict__ deg, int* __restrict__ rp) {
    __shared__ int a[NN], b[NN];
    int t = threadIdx.x;                       // 1024 threads
    for (int i = t; i < NN; i += 1024) a[i] = deg[i];
    __syncthreads();
    int* src = a; int* dst = b;
    for (int off = 1; off < NN; off <<= 1) {
        for (int i = t; i < NN; i += 1024)
            dst[i] = src[i] + (i >= off ? src[i - off] : 0);
        __syncthreads();
        int* tmp = src; src = dst; dst = tmp;
    }
    for (int i = t; i < NN; i += 1024) rp[i + 1] = src[i];
    if (t == 0) rp[0] = 0;
}

__global__ void k_fill(const float* __restrict__ adj, const int* __restrict__ rp,
                       int* __restrict__ ci) {
    int gw   = (blockIdx.x * blockDim.x + threadIdx.x) >> 6;
    int lane = threadIdx.x & 63;
    if (gw >= NN) return;
    const float* row = adj + (size_t)gw * NN;
    int base = rp[gw];
    for (int j0 = 0; j0 < NN; j0 += 64) {
        bool v = row[j0 + lane] > 0.f;
        unsigned long long m = __ballot(v);
        int pos = __popcll(m & ((1ULL << lane) - 1ULL));
        if (v) ci[base + pos] = j0 + lane;
        base += __popcll(m);
    }
}

// ---------------- split fp32 -> bf16 hi/lo (elementwise, for input x) ----------------
__global__ void k_split(const float* __restrict__ src, unsigned short* __restrict__ hi,
                        unsigned short* __restrict__ lo, int n4) {
    int i = blockIdx.x * 256 + threadIdx.x;
    if (i >= n4) return;
    float4 v = ((const float4*)src)[i];
    ushort4 h, l;
    h.x = f2bf(v.x); l.x = f2bf(v.x - bf2f(h.x));
    h.y = f2bf(v.y); l.y = f2bf(v.y - bf2f(h.y));
    h.z = f2bf(v.z); l.z = f2bf(v.z - bf2f(h.z));
    h.w = f2bf(v.w); l.w = f2bf(v.w - bf2f(h.w));
    ((ushort4*)hi)[i] = h;
    ((ushort4*)lo)[i] = l;
}

// ------- ALL weight transposes+splits in ONE launch ----
struct TSDesc {
    const float* B[12];
    unsigned short* bh[12];
    unsigned short* bl[12];
    int K[12], Nc[12], hs[12];
    int start[13];
};

__global__ __launch_bounds__(256) void k_tsplit_all(TSDesc d) {
    __shared__ float t[64][65];
    int b = blockIdx.x;
    int s = 0;
    while (b >= d.start[s + 1]) s++;
    int lb = b - d.start[s];
    int K = d.K[s], Nc = d.Nc[s], hs = d.hs[s];
    int tilesX = K >> 6;
    int kb = (lb % tilesX) * 64, cb = (lb / tilesX) * 64;
    const float* B = d.B[s];
    unsigned short* bth = d.bh[s];
    unsigned short* btl = d.bl[s];

    int tid = threadIdx.x;
    #pragma unroll
    for (int i = 0; i < 16; i++) {
        int idx = i * 256 + tid;
        int kk = idx >> 6, cc = idx & 63;
        int c = cb + cc, k = kb + kk;
        float v;
        if (hs < 0) v = B[(size_t)k * Nc + c];
        else {
            int hid = 1 << hs; int head = c >> hs; int dd = c & (hid - 1);
            v = B[((size_t)head * K + k) * hid + dd];
        }
        t[kk][cc] = v;
    }
    __syncthreads();
    #pragma unroll
    for (int i = 0; i < 16; i++) {
        int idx = i * 256 + tid;
        int cc = idx >> 6, kk = idx & 63;
        float v = t[kk][cc];
        unsigned short h = f2bf(v);
        size_t o = (size_t)(cb + cc) * K + kb + kk;
        bth[o] = h;
        btl[o] = f2bf(v - bf2f(h));
    }
}

// ---------------- split-bf16 MFMA GEMM with fused attention-score epilogue --------
// OUT=0: write bf16-hi output to Cb (no atomics; single K pass).
// OUT=1: atomicAdd fp32 into Cf (split-K).
// Fused: sg1[head*NN+row] += sum_d C[row,d]*av[d]; sg2 with av[d+aoff].
template<int OUT>
__global__ __launch_bounds__(256) void k_mfma(
    const unsigned short* __restrict__ Ah, const unsigned short* __restrict__ Al,
    const unsigned short* __restrict__ Bh, const unsigned short* __restrict__ Bl,
    float* __restrict__ Cf, unsigned short* __restrict__ Cb, int Nc, int K, int Kc,
    const float* __restrict__ avec, float* __restrict__ sg1, float* __restrict__ sg2,
    int hs, int aoff)
{
    __shared__ unsigned short lds[16384];
    int tid = threadIdx.x, lane = tid & 63, w = tid >> 6;
    int m0 = blockIdx.y * 128, n0 = blockIdx.x * 128;
    int kbeg = blockIdx.z * Kc;

    int sA = tid, sB = 256 + tid;
    int ra = sA >> 2, ga = ((sA & 3) - (ra >> 1)) & 3;
    int rb = sB >> 2, gb = ((sB & 3) - (rb >> 1)) & 3;
    const unsigned short* pAh0 = Ah + (size_t)(m0 + ra) * K + kbeg + ga * 8;
    const unsigned short* pAh1 = Ah + (size_t)(m0 + rb) * K + kbeg + gb * 8;
    const unsigned short* pAl0 = Al + (size_t)(m0 + ra) * K + kbeg + ga * 8;
    const unsigned short* pAl1 = Al + (size_t)(m0 + rb) * K + kbeg + gb * 8;
    const unsigned short* pBh0 = Bh + (size_t)(n0 + ra) * K + kbeg + ga * 8;
    const unsigned short* pBh1 = Bh + (size_t)(n0 + rb) * K + kbeg + gb * 8;
    const unsigned short* pBl0 = Bl + (size_t)(n0 + ra) * K + kbeg + ga * 8;
    const unsigned short* pBl1 = Bl + (size_t)(n0 + rb) * K + kbeg + gb * 8;
    unsigned short* d0 = &lds[(w * 64) * 8];
    unsigned short* d1 = &lds[(256 + w * 64) * 8];

    int wr = w >> 1, wc = w & 1;
    int offA[4], offB[4];
    #pragma unroll
    for (int m = 0; m < 4; m++) {
        int row = wr * 64 + m * 16 + (lane & 15); int g = lane >> 4;
        offA[m] = (row * 4 + ((g + (row >> 1)) & 3)) * 8;
    }
    #pragma unroll
    for (int n = 0; n < 4; n++) {
        int row = wc * 64 + n * 16 + (lane & 15); int g = lane >> 4;
        offB[n] = (row * 4 + ((g + (row >> 1)) & 3)) * 8;
    }

    f32x4 acc[4][4];
    #pragma unroll
    for (int m = 0; m < 4; m++)
        #pragma unroll
        for (int n = 0; n < 4; n++) acc[m][n] = (f32x4){0.f, 0.f, 0.f, 0.f};

    int nk = Kc >> 5;
    for (int ks = 0; ks < nk; ks++) {
        gload16(pAh0, d0);          gload16(pAh1, d1);
        gload16(pAl0, d0 + 4096);   gload16(pAl1, d1 + 4096);
        gload16(pBh0, d0 + 8192);   gload16(pBh1, d1 + 8192);
        gload16(pBl0, d0 + 12288);  gload16(pBl1, d1 + 12288);
        pAh0 += 32; pAh1 += 32; pAl0 += 32; pAl1 += 32;
        pBh0 += 32; pBh1 += 32; pBl0 += 32; pBl1 += 32;
        __syncthreads();
        bf16x8 ah[4], al[4], bh[4], bl[4];
        #pragma unroll
        for (int m = 0; m < 4; m++) {
            ah[m] = *(const bf16x8*)&lds[offA[m]];
            al[m] = *(const bf16x8*)&lds[4096 + offA[m]];
        }
        #pragma unroll
        for (int n = 0; n < 4; n++) {
            bh[n] = *(const bf16x8*)&lds[8192 + offB[n]];
            bl[n] = *(const bf16x8*)&lds[12288 + offB[n]];
        }
        #pragma unroll
        for (int m = 0; m < 4; m++)
            #pragma unroll
            for (int n = 0; n < 4; n++) {
                acc[m][n] = __builtin_amdgcn_mfma_f32_16x16x32_bf16(ah[m], bh[n], acc[m][n], 0, 0, 0);
                acc[m][n] = __builtin_amdgcn_mfma_f32_16x16x32_bf16(al[m], bh[n], acc[m][n], 0, 0, 0);
                acc[m][n] = __builtin_amdgcn_mfma_f32_16x16x32_bf16(ah[m], bl[n], acc[m][n], 0, 0, 0);
            }
        __syncthreads();
    }

    // C write
    #pragma unroll
    for (int m = 0; m < 4; m++)
        #pragma unroll
        for (int n = 0; n < 4; n++) {
            int row = m0 + wr * 64 + m * 16 + (lane >> 4) * 4;
            int col = n0 + wc * 64 + n * 16 + (lane & 15);
            #pragma unroll
            for (int r = 0; r < 4; r++) {
                float v = acc[m][n][r];
                if (OUT == 0) Cb[(size_t)(row + r) * Nc + col] = f2bf(v);
                else          atomicAdd(&Cf[(size_t)(row + r) * Nc + col], v);
            }
        }

    // fused s1/s2 epilogue
    int head = (hs >= 0) ? (n0 >> hs) : 0;
    const float* ab = avec + head * 2 * aoff;
    float av1[4], av2[4];
    int colbase = n0 + wc * 64 + (lane & 15);
    #pragma unroll
    for (int n = 0; n < 4; n++) {
        int c = colbase + n * 16;
        int dd = (hs >= 0) ? (c & (aoff - 1)) : c;
        av1[n] = ab[dd];
        av2[n] = ab[dd + aoff];
    }
    #pragma unroll
    for (int m = 0; m < 4; m++)
        #pragma unroll
        for (int r = 0; r < 4; r++) {
            float p1 = 0.f, p2 = 0.f;
            #pragma unroll
            for (int n = 0; n < 4; n++) {
                float v = acc[m][n][r];
                p1 += v * av1[n];
                p2 += v * av2[n];
            }
            #pragma unroll
            for (int o = 1; o < 16; o <<= 1) {
                p1 += __shfl_xor(p1, o);
                p2 += __shfl_xor(p2, o);
            }
            if ((lane & 15) == 0) {
                int row = m0 + wr * 64 + m * 16 + (lane >> 4) * 4 + r;
                atomicAdd(&sg1[head * NN + row], p1);
                atomicAdd(&sg2[head * NN + row], p2);
            }
        }
}

// ------------- BIG agg: bf16 gather, per (node,head), XCD<->head affinity -------------
// hh: bf16-hi h [NN][HD]. Gathers ushort8 (8 cols / thread). Writes bf16 hi/lo split.
__global__ __launch_bounds__(256) void k_aggb(
    const unsigned short* __restrict__ hh, const float* __restrict__ s1,
    const float* __restrict__ s2, const int* __restrict__ rp, const int* __restrict__ ci,
    unsigned short* __restrict__ outH, unsigned short* __restrict__ outL,
    int hid, int HD, int c8sh)
{
    __shared__ float    w[CHUNK];
    __shared__ unsigned cols[CHUNK];      // uint4-unit row offsets
    __shared__ float    redbuf[2048];     // 8 floats/thread
    __shared__ float    red[8];

    int blk  = blockIdx.x;
    int head = blk & (NH - 1);
    int i    = blk >> 3;
    int tid = threadIdx.x, lane = tid & 63, wid = tid >> 6;
    int base = rp[i], deg = rp[i + 1] - base;
    float s1i = s1[head * NN + i];
    const float* s2h = s2 + head * NN;

    int C8  = 1 << c8sh;                  // ushort8 cols per head slice
    int G   = 256 >> c8sh;                // neighbor groups
    int col = tid & (C8 - 1);
    int grp = tid >> c8sh;

    const uint4* h4 = (const uint4*)hh;
    unsigned hoff8 = (unsigned)(head * hid) >> 3;
    unsigned ld8   = (unsigned)HD >> 3;

    float m_run = -1e30f, s_run = 0.f;
    float a0=0,a1=0,a2=0,a3=0,a4=0,a5=0,a6=0,a7=0;

    for (int k0 = 0; k0 < deg; k0 += CHUNK) {
        int n = min(CHUNK, deg - k0);
        __syncthreads();
        float m = -1e30f;
        for (int k = tid; k < n; k += 256) {
            int j = ci[base + k0 + k];
            float e = lrelu(s1i + s2h[j]);
            cols[k] = (unsigned)j * ld8 + hoff8;
            w[k] = e;
            m = fmaxf(m, e);
        }
        #pragma unroll
        for (int off = 32; off; off >>= 1) m = fmaxf(m, __shfl_down(m, off));
        if (lane == 0) red[wid] = m;
        __syncthreads();
        float bm = fmaxf(fmaxf(red[0], red[1]), fmaxf(red[2], red[3]));
        float m2 = fmaxf(m_run, bm);

        float sum = 0.f;
        for (int k = tid; k < n; k += 256) {
            float wv = expf(w[k] - m2);
            w[k] = wv;
            sum += wv;
        }
        #pragma unroll
        for (int off = 32; off; off >>= 1) sum += __shfl_down(sum, off);
        if (lane == 0) red[4 + wid] = sum;
        __syncthreads();
        float csum = red[4] + red[5] + red[6] + red[7];

        float scale = expf(m_run - m2);
        s_run = s_run * scale + csum;
        a0*=scale; a1*=scale; a2*=scale; a3*=scale;
        a4*=scale; a5*=scale; a6*=scale; a7*=scale;
        m_run = m2;

        // gather, 2-way unrolled with dual accumulators
        float q0=0,q1=0,q2=0,q3=0,q4=0,q5=0,q6=0,q7=0;
        int k = grp;
        for (; k + G < n; k += 2 * G) {
            float w0 = w[k], w1 = w[k + G];
            uint4 u0 = h4[cols[k]     + col];
            uint4 u1 = h4[cols[k + G] + col];
            a0 += w0 * blo(u0.x); a1 += w0 * bhi(u0.x);
            a2 += w0 * blo(u0.y); a3 += w0 * bhi(u0.y);
            a4 += w0 * blo(u0.z); a5 += w0 * bhi(u0.z);
            a6 += w0 * blo(u0.w); a7 += w0 * bhi(u0.w);
            q0 += w1 * blo(u1.x); q1 += w1 * bhi(u1.x);
            q2 += w1 * blo(u1.y); q3 += w1 * bhi(u1.y);
            q4 += w1 * blo(u1.z); q5 += w1 * bhi(u1.z);
            q6 += w1 * blo(u1.w); q7 += w1 * bhi(u1.w);
        }
        if (k < n) {
            float w0 = w[k];
            uint4 u0 = h4[cols[k] + col];
            a0 += w0 * blo(u0.x); a1 += w0 * bhi(u0.x);
            a2 += w0 * blo(u0.y); a3 += w0 * bhi(u0.y);
            a4 += w0 * blo(u0.z); a5 += w0 * bhi(u0.z);
            a6 += w0 * blo(u0.w); a7 += w0 * bhi(u0.w);
        }
        a0+=q0; a1+=q1; a2+=q2; a3+=q3; a4+=q4; a5+=q5; a6+=q6; a7+=q7;
    }

    // cross-group reduction
    redbuf[0*256+tid]=a0; redbuf[1*256+tid]=a1; redbuf[2*256+tid]=a2; redbuf[3*256+tid]=a3;
    redbuf[4*256+tid]=a4; redbuf[5*256+tid]=a5; redbuf[6*256+tid]=a6; redbuf[7*256+tid]=a7;
    __syncthreads();
    if (grp == 0) {
        float v[8];
        #pragma unroll
        for (int e = 0; e < 8; e++) {
            float s = 0.f;
            for (int g = 0; g < G; g++) s += redbuf[e * 256 + g * C8 + col];
            v[e] = s;
        }
        float inv = 1.f / s_run;
        #pragma unroll
        for (int e = 0; e < 8; e++) v[e] = elu(v[e] * inv);
        unsigned short hh_[8], ll_[8];
        #pragma unroll
        for (int e = 0; e < 8; e++) {
            hh_[e] = f2bf(v[e]);
            ll_[e] = f2bf(v[e] - bf2f(hh_[e]));
        }
        size_t ob = ((size_t)i * HD + head * hid) >> 3;   // uint4 units
        uint4 ph, pl;
        ph.x = (unsigned)hh_[0] | ((unsigned)hh_[1] << 16);
        ph.y = (unsigned)hh_[2] | ((unsigned)hh_[3] << 16);
        ph.z = (unsigned)hh_[4] | ((unsigned)hh_[5] << 16);
        ph.w = (unsigned)hh_[6] | ((unsigned)hh_[7] << 16);
        pl.x = (unsigned)ll_[0] | ((unsigned)ll_[1] << 16);
        pl.y = (unsigned)ll_[2] | ((unsigned)ll_[3] << 16);
        pl.z = (unsigned)ll_[4] | ((unsigned)ll_[5] << 16);
        pl.w = (unsigned)ll_[6] | ((unsigned)ll_[7] << 16);
        ((uint4*)outH)[ob + col] = ph;
        ((uint4*)outL)[ob + col] = pl;
    }
}

// ------------- SMALL agg: fp32 gather from ho, 128-col slices (SC blocks/node) -------------
__global__ __launch_bounds__(256) void k_aggs(
    const float* __restrict__ hsrc, const float* __restrict__ t1, const float* __restrict__ t2,
    const int* __restrict__ rp, const int* __restrict__ ci,
    float* __restrict__ outF, unsigned short* __restrict__ outH, unsigned short* __restrict__ outL,
    int fout, int SC)
{
    __shared__ float    w[CHUNK];
    __shared__ unsigned cols[CHUNK];      // float4-unit offsets (incl. slice)
    __shared__ float4   redbuf[256];
    __shared__ float    red[8];

    int blk = blockIdx.x;
    int i   = blk / SC;
    int sc  = blk - i * SC;
    int tid = threadIdx.x, lane = tid & 63, wid = tid >> 6;
    int base = rp[i], deg = rp[i + 1] - base;
    float s1i = t1[i];

    int col = tid & 31;           // C4 = 32 (128 cols per slice)
    int grp = tid >> 5;           // G = 8

    const float4* h4 = (const float4*)hsrc;
    unsigned soff4 = (unsigned)sc * 32;
    unsigned ld4   = (unsigned)fout >> 2;

    float m_run = -1e30f, s_run = 0.f;
    float4 acc = make_float4(0.f, 0.f, 0.f, 0.f);

    for (int k0 = 0; k0 < deg; k0 += CHUNK) {
        int n = min(CHUNK, deg - k0);
        __syncthreads();
        float m = -1e30f;
        for (int k = tid; k < n; k += 256) {
            int j = ci[base + k0 + k];
            float e = lrelu(s1i + t2[j]);
            cols[k] = (unsigned)j * ld4 + soff4;
            w[k] = e;
            m = fmaxf(m, e);
        }
        #pragma unroll
        for (int off = 32; off; off >>= 1) m = fmaxf(m, __shfl_down(m, off));
        if (lane == 0) red[wid] = m;
        __syncthreads();
        float bm = fmaxf(fmaxf(red[0], red[1]), fmaxf(red[2], red[3]));
        float m2 = fmaxf(m_run, bm);

        float sum = 0.f;
        for (int k = tid; k < n; k += 256) {
            float wv = expf(w[k] - m2);
            w[k] = wv;
            sum += wv;
        }
        #pragma unroll
        for (int off = 32; off; off >>= 1) sum += __shfl_down(sum, off);
        if (lane == 0) red[4 + wid] = sum;
        __syncthreads();
        float csum = red[4] + red[5] + red[6] + red[7];

        float scale = expf(m_run - m2);
        s_run = s_run * scale + csum;
        acc.x *= scale; acc.y *= scale; acc.z *= scale; acc.w *= scale;
        m_run = m2;

        float4 q1 = make_float4(0,0,0,0), q2 = make_float4(0,0,0,0), q3 = make_float4(0,0,0,0);
        int k = grp;
        for (; k + 24 < n; k += 32) {        // 4-way unroll, G=8
            float w0 = w[k], w1 = w[k + 8], w2 = w[k + 16], w3 = w[k + 24];
            float4 h0 = h4[cols[k]      + col];
            float4 h1 = h4[cols[k + 8]  + col];
            float4 h2 = h4[cols[k + 16] + col];
            float4 h3 = h4[cols[k + 24] + col];
            acc.x += w0 * h0.x; acc.y += w0 * h0.y; acc.z += w0 * h0.z; acc.w += w0 * h0.w;
            q1.x  += w1 * h1.x; q1.y  += w1 * h1.y; q1.z  += w1 * h1.z; q1.w  += w1 * h1.w;
            q2.x  += w2 * h2.x; q2.y  += w2 * h2.y; q2.z  += w2 * h2.z; q2.w  += w2 * h2.w;
            q3.x  += w3 * h3.x; q3.y  += w3 * h3.y; q3.z  += w3 * h3.z; q3.w  += w3 * h3.w;
        }
        for (; k < n; k += 8) {
            float w0 = w[k];
            float4 h0 = h4[cols[k] + col];
            acc.x += w0 * h0.x; acc.y += w0 * h0.y; acc.z += w0 * h0.z; acc.w += w0 * h0.w;
        }
        acc.x += q1.x + q2.x + q3.x; acc.y += q1.y + q2.y + q3.y;
        acc.z += q1.z + q2.z + q3.z; acc.w += q1.w + q2.w + q3.w;
    }

    redbuf[tid] = acc;
    __syncthreads();
    if (grp == 0) {      // tid < 32
        #pragma unroll
        for (int g = 1; g < 8; g++) {
            float4 o = redbuf[g * 32 + col];
            acc.x += o.x; acc.y += o.y; acc.z += o.z; acc.w += o.w;
        }
        float inv = 1.f / s_run;
        float4 val;
        val.x = elu(acc.x * inv); val.y = elu(acc.y * inv);
        val.z = elu(acc.z * inv); val.w = elu(acc.w * inv);
        size_t o4 = (size_t)i * ld4 + soff4 + col;
        if (outF) ((float4*)outF)[o4] = val;
        ushort4 h, l;
        h.x = f2bf(val.x); l.x = f2bf(val.x - bf2f(h.x));
        h.y = f2bf(val.y); l.y = f2bf(val.y - bf2f(h.y));
        h.z = f2bf(val.z); l.z = f2bf(val.z - bf2f(h.z));
        h.w = f2bf(val.w); l.w = f2bf(val.w - bf2f(h.w));
        ((ushort4*)outH)[o4] = h;
        ((ushort4*)outL)[o4] = l;
    }
}

// ---------------- host driver ----------------
extern "C" void kernel_launch(void* const* d_in, const int* in_sizes, int n_in,
                              void* d_out, int out_size, void* d_ws, size_t ws_size,
                              hipStream_t stream)
{
    const float* x   = (const float*)d_in[0];
    const float* adj = (const float*)d_in[1];
    struct L { int fin, hid, fout; };
    const L dims[6] = {{256,128,128},{128,256,256},{256,512,384},
                       {384,512,256},{256,256,128},{128,128,256}};
    const int SKwo[6] = {16, 8, 8, 8, 16, 8};

    char* ws = (char*)d_ws;
    size_t off = 0;
    auto alloc = [&](size_t bytes) -> void* {
        void* p = ws + off;
        off = (off + bytes + 255) & ~(size_t)255;
        return p;
    };
    int*   rp   = (int*)alloc((NN + 1) * sizeof(int));
    int*   deg  = (int*)alloc(NN * sizeof(int));
    int*   ci   = (int*)alloc((size_t)(1 << 20) * sizeof(int));
    unsigned short* hh = (unsigned short*)alloc((size_t)NN * 4096 * 2);   // bf16-hi h
    unsigned short* ghi = (unsigned short*)alloc((size_t)NN * 4096 * 2);
    unsigned short* glo = (unsigned short*)alloc((size_t)NN * 4096 * 2);
    float* hob = (float*)alloc((size_t)NN * 512 * sizeof(float));
    unsigned short* xhi = (unsigned short*)alloc((size_t)NN * 512 * 2);
    unsigned short* xlo = (unsigned short*)alloc((size_t)NN * 512 * 2);
    float* sbuf = (float*)alloc((size_t)(2 * NH * NN + 2 * NN) * sizeof(float));
    float* s1 = sbuf;
    float* s2 = sbuf + NH * NN;
    float* t1 = sbuf + 2 * NH * NN;
    float* t2 = t1 + NN;

    unsigned short* whh[6]; unsigned short* whl[6];
    unsigned short* woh[6]; unsigned short* wol[6];
    TSDesc td;
    int nblk = 0;
    for (int l = 0; l < 6; l++) {
        int fin = dims[l].fin, hid = dims[l].hid, fout = dims[l].fout;
        int HD = NH * hid;
        size_t szWh = (size_t)fin * HD, szWo = (size_t)HD * fout;
        whh[l] = (unsigned short*)alloc(szWh * 2);
        whl[l] = (unsigned short*)alloc(szWh * 2);
        woh[l] = (unsigned short*)alloc(szWo * 2);
        wol[l] = (unsigned short*)alloc(szWo * 2);
        int hs = (hid == 128) ? 7 : (hid == 256) ? 8 : 9;
        td.B[2*l] = (const float*)d_in[2 + l * 4 + 0];
        td.bh[2*l] = whh[l]; td.bl[2*l] = whl[l];
        td.K[2*l] = fin; td.Nc[2*l] = HD; td.hs[2*l] = hs;
        td.start[2*l] = nblk; nblk += (fin / 64) * (HD / 64);
        td.B[2*l+1] = (const float*)d_in[2 + l * 4 + 2];
        td.bh[2*l+1] = woh[l]; td.bl[2*l+1] = wol[l];
        td.K[2*l+1] = HD; td.Nc[2*l+1] = fout; td.hs[2*l+1] = -1;
        td.start[2*l+1] = nblk; nblk += (HD / 64) * (fout / 64);
    }
    td.start[12] = nblk;

    // ---- front matter ----
    k_count<<<NN / 4, 256, 0, stream>>>(adj, deg);
    k_scan <<<1, 1024, 0, stream>>>(deg, rp);
    k_fill <<<NN / 4, 256, 0, stream>>>(adj, rp, ci);
    k_split<<<(NN * 256 / 4 + 255) / 256, 256, 0, stream>>>(x, xhi, xlo, NN * 256 / 4);
    k_tsplit_all<<<nblk, 256, 0, stream>>>(td);

    for (int l = 0; l < 6; l++) {
        int fin = dims[l].fin, hid = dims[l].hid, fout = dims[l].fout;
        int HD = NH * hid;
        int hs = (hid == 128) ? 7 : (hid == 256) ? 8 : 9;
        int c8sh = hs - 3;                     // log2(hid/8)
        const float* ah = (const float*)d_in[2 + l * 4 + 1];
        const float* ao = (const float*)d_in[2 + l * 4 + 3];

        hipMemsetAsync(sbuf, 0, (size_t)(2 * NH * NN + 2 * NN) * sizeof(float), stream);

        // --- h = x @ Wh  (bf16-hi out + fused s1/s2) ---
        dim3 gg1(HD / 128, NN / 128, 1);
        k_mfma<0><<<gg1, 256, 0, stream>>>(xhi, xlo, whh[l], whl[l], nullptr, hh, HD,
                                           fin, fin, ah, s1, s2, hs, hid);

        // per-head masked softmax aggregation (bf16 gather, XCD-head affinity)
        k_aggb<<<NN * NH, 256, 0, stream>>>(hh, s1, s2, rp, ci, ghi, glo, hid, HD, c8sh);

        // --- ho = hcat @ Wo  (split-K fp32 + fused t1/t2) ---
        int sko = SKwo[l];
        hipMemsetAsync(hob, 0, (size_t)NN * fout * 4, stream);
        dim3 gg2(fout / 128, NN / 128, sko);
        k_mfma<1><<<gg2, 256, 0, stream>>>(ghi, glo, woh[l], wol[l], hob, nullptr, fout,
                                           HD, HD / sko, ao, t1, t2, -1, fout);

        float* outF = (l == 5) ? (float*)d_out : nullptr;
        int SC = fout >> 7;                    // fout/128
        k_aggs<<<NN * SC, 256, 0, stream>>>(hob, t1, t2, rp, ci, outF, xhi, xlo, fout, SC);
    }
}